// Round 3
// baseline (11206.579 us; speedup 1.0000x reference)
//
#include <hip/hip_runtime.h>
#include <hip/hip_bf16.h>
#include <math.h>

// ---------------- constants (fixed by setup_inputs) ----------------
constexpr int B   = 128;   // batch
constexpr int N1  = 32;    // agents (1 ego + 31 veh)
constexpr int HH  = 20;    // history steps (T-2)
constexpr int L   = 64;    // lanes
constexpr int PTS = 10;    // points per lane
constexpr int F   = 128;   // feature size
constexpr int LF  = 64;    // lane feature
constexpr int NH  = 8;     // heads
constexpr int HD  = 16;    // head dim
constexpr int KVN = 96;    // kv tokens = 32 agents + 64 lanes
constexpr int G4  = 512;   // 4*F lstm gates
constexpr int NP  = 6;     // num preds
constexpr int P6  = 36;    // NP*6
constexpr int LEN = 30;    // len_pred

__device__ __forceinline__ float fsigmoid(float x) { return 1.f / (1.f + __expf(-x)); }
__device__ __forceinline__ float ftanh(float x)    { return 1.f - 2.f / (__expf(2.f * x) + 1.f); }

// ---------------- one-time kernels ----------------

__global__ void k_lane_tok(const float* __restrict__ lane_input,
                           const float* __restrict__ w1, const float* __restrict__ b1,
                           const float* __restrict__ w2, const float* __restrict__ b2,
                           const float* __restrict__ to_f,
                           float* __restrict__ kvbuf) {
    int bl = blockIdx.x; int b = bl / L, l = bl % L;
    int tid = threadIdx.x; // 64 threads
    __shared__ float h1[LF][16];
    __shared__ float m[LF];
    const float* xin = lane_input + ((size_t)(b * L + l) * PTS) * 2;
    float w10 = w1[tid], w11 = w1[LF + tid], bb1 = b1[tid];
#pragma unroll
    for (int p = 0; p < PTS; ++p) {
        float v = xin[p * 2] * w10 + xin[p * 2 + 1] * w11 + bb1;
        h1[tid][p] = fmaxf(v, 0.f);
    }
    __syncthreads();
    float ap[PTS];
    float bb2 = b2[tid];
#pragma unroll
    for (int p = 0; p < PTS; ++p) ap[p] = bb2;
    for (int h = 0; h < LF; ++h) {
        float w2v = w2[h * LF + tid];
        float4 x0 = *(const float4*)&h1[h][0];
        float4 x1 = *(const float4*)&h1[h][4];
        float2 x2 = *(const float2*)&h1[h][8];
        ap[0] += x0.x * w2v; ap[1] += x0.y * w2v; ap[2] += x0.z * w2v; ap[3] += x0.w * w2v;
        ap[4] += x1.x * w2v; ap[5] += x1.y * w2v; ap[6] += x1.z * w2v; ap[7] += x1.w * w2v;
        ap[8] += x2.x * w2v; ap[9] += x2.y * w2v;
    }
    float acc = 0.f;
#pragma unroll
    for (int p = 0; p < PTS; ++p) acc += fmaxf(ap[p], 0.f);
    m[tid] = acc * (1.f / PTS);
    __syncthreads();
    float* outp = kvbuf + ((size_t)(b * KVN) + 32 + l) * F;
    for (int f = tid; f < F; f += LF) {
        float s = 0.f;
        for (int j = 0; j < LF; ++j) s += m[j] * to_f[j * F + f];
        outp[f] = s;
    }
}

__global__ void k_lane_kv(const float* __restrict__ kvbuf,
                          const float* __restrict__ wk, const float* __restrict__ wv,
                          float* __restrict__ kb, float* __restrict__ vb) {
    int g = blockIdx.x & 7, b = blockIdx.x >> 3;
    int n0 = 32 + g * 8;
    int tid = threadIdx.x; // 256
    int j = tid & 127, rh = tid >> 7;
    __shared__ float tok[8][F];
    for (int i = tid; i < 8 * F; i += 256) {
        int r = i >> 7, c = i & 127;
        tok[r][c] = kvbuf[((size_t)b * KVN + n0 + r) * F + c];
    }
    __syncthreads();
    float ak[4] = {0, 0, 0, 0}, av[4] = {0, 0, 0, 0};
    int r0 = rh * 4;
    for (int k2 = 0; k2 < F; ++k2) {
        float wkv = wk[k2 * F + j], wvv = wv[k2 * F + j];
#pragma unroll
        for (int r = 0; r < 4; ++r) {
            float x = tok[r0 + r][k2];
            ak[r] += x * wkv; av[r] += x * wvv;
        }
    }
#pragma unroll
    for (int r = 0; r < 4; ++r) {
        int n = n0 + r0 + r;
        kb[((size_t)b * KVN + n) * F + j] = ak[r];
        vb[((size_t)b * KVN + n) * F + j] = av[r];
    }
}

__global__ void k_hist_pos(const float* __restrict__ input,
                           const float* __restrict__ init_pos,
                           float* __restrict__ hist_pos,
                           float* __restrict__ pred_pos) {
    int idx = blockIdx.x * blockDim.x + threadIdx.x;
    if (idx >= B * N1) return;
    float px = init_pos[idx * 2], py = init_pos[idx * 2 + 1];
    int b = idx / N1, n = idx % N1;
    for (int t = 0; t < HH; ++t) {
        const float* ip = input + ((size_t)(t * B + b) * N1 + n) * 2;
        float dl = ip[0], yaw = ip[1];
        px += dl * cosf(yaw);
        py += dl * sinf(yaw);
        float* hp = hist_pos + ((size_t)(t * B + b) * N1 + n) * 2;
        hp[0] = px; hp[1] = py;
    }
#pragma unroll
    for (int p = 0; p < NP; ++p) {
        pred_pos[((size_t)idx * NP + p) * 2 + 0] = px;
        pred_pos[((size_t)idx * NP + p) * 2 + 1] = py;
    }
}

// veh LSTM weights: [k][part(ih/hh)][f] float4-of-gates, contiguous for chunked staging
// vehW9 float idx = (((k*2 + part)*128 + f)*4 + g) = (part?whh:wih)[(g*128+f)*128 + k]
__global__ void k_build_w9(const float* __restrict__ wih, const float* __restrict__ whh,
                           float* __restrict__ w9) {
    int i = blockIdx.x * blockDim.x + threadIdx.x;
    if (i >= 128 * 128 * 8) return;
    int g = i & 3, f = (i >> 2) & 127, part = (i >> 9) & 1, k = i >> 10;
    const float* src = part ? whh : wih;
    w9[i] = src[((size_t)(g * 128 + f)) * 128 + k];
}

// ego LSTM weights gate-parallel: egoP[((k4*512 + j)*2 + s)*4 + kk] = W_s[j][k4*4+kk]
__global__ void k_build_egoP(const float* __restrict__ wih, const float* __restrict__ whh,
                             float* __restrict__ egoP) {
    int i = blockIdx.x * blockDim.x + threadIdx.x;
    if (i >= 32 * 512 * 8) return;
    int kk = i & 3, s = (i >> 2) & 1, j = (i >> 3) & 511, k4 = i >> 12;
    int k = k4 * 4 + kk;
    egoP[i] = (s == 0) ? wih[(size_t)j * 128 + k] : whh[(size_t)j * 128 + k];
}

// pack {wq,wk,wv} as float3 per (k,f), contiguous [k][f]
__global__ void k_build_wqkv3(const float* __restrict__ wq, const float* __restrict__ wk,
                              const float* __restrict__ wv, float* __restrict__ o3) {
    int i = blockIdx.x * blockDim.x + threadIdx.x;
    if (i >= 128 * 128) return;
    o3[i * 3 + 0] = wq[i]; o3[i * 3 + 1] = wk[i]; o3[i * 3 + 2] = wv[i];
}

// transposed output-head weights: oWT[(m*36+jj)*128 + k] = W_m[k*36+jj]
__global__ void k_build_oWT(const float* __restrict__ oe_w, const float* __restrict__ ov_w,
                            float* __restrict__ oWT) {
    int i = blockIdx.x * blockDim.x + threadIdx.x;
    if (i >= 2 * 36 * 128) return;
    int m = i / 4608, r = i % 4608, jj = r >> 7, k = r & 127;
    oWT[i] = (m == 0) ? oe_w[(size_t)k * 36 + jj] : ov_w[(size_t)k * 36 + jj];
}

// ---------------- persistent per-batch mega kernel ----------------
// LDS: Kbuf 49536 + Vt 51200 + tok 16384 + qs 16384 + hs 16384 + sc 12288 + mk 384 = 162560 B
// Dead-region reuse as weight-staging double buffers:
//   QKV phase : bufA = Kbuf[0..3072)   bufB = scF[0..3072)    (12 KB chunks of wqkv3)
//   LSTM phase: bufA = Kbuf[0..4096)   bufB = qsS[0..4096)    (16 KB chunks of vehW9)
__global__ __launch_bounds__(1024, 4) void k_mega(
    const float* __restrict__ input, const float* __restrict__ hist_pos,
    const float* __restrict__ conv_w, const float* __restrict__ conv_b,
    const float* __restrict__ pos_w, const float* __restrict__ pos_b,
    const float* __restrict__ wqkv3, const float* __restrict__ wo,
    const float* __restrict__ ln_ego_g, const float* __restrict__ ln_ego_b,
    const float* __restrict__ ln_g, const float* __restrict__ ln_b,
    const float* __restrict__ egoP2, const float* __restrict__ vehW9,
    const float* __restrict__ ego_bih, const float* __restrict__ ego_bhh,
    const float* __restrict__ veh_bih, const float* __restrict__ veh_bhh,
    const float* __restrict__ oWT,
    const float* __restrict__ out_ego_b, const float* __restrict__ out_b,
    const float* __restrict__ mask_input, const float* __restrict__ lane_mask,
    const float* __restrict__ lane_kb, const float* __restrict__ lane_vb,
    float* __restrict__ pred_pos, float* __restrict__ cbuf,
    float* __restrict__ out)
{
    const int b = blockIdx.x;
    const int tid = threadIdx.x;

    __shared__ float  Kbuf[96 * 129];   // K[kvrow][feat], pad 129; rows 0-31 double as staging
    __shared__ float4 Vt4[128 * 25];    // V^T[feat][kvrow], stride 100 floats
    __shared__ float  tokS[32 * 128];   // tokens -> residual -> x (LN'd)
    __shared__ float  qsS[32 * 128];    // q / attn-out; doubles as LSTM staging buf B
    __shared__ float  hsS[32 * 128];    // LSTM h, persistent
    __shared__ float4 sc4[32 * 24];     // probs [32][96]; QKV staging buf B; ego/o36 scratch
    __shared__ float  mkS[96];

    float* VtF = (float*)Vt4;
    float* scF = (float*)sc4;

    const int f  = tid & 127;
    const int ng = tid >> 7;      // 8 agent-groups of 4
    const int n0 = ng * 4;
    const int jg = tid >> 1;      // ego gate index 0..511
    const int kh = tid & 1;       // ego k-half

    float bv[4];
#pragma unroll
    for (int g = 0; g < 4; ++g) bv[g] = veh_bih[g * 128 + f] + veh_bhh[g * 128 + f];
    const float bsumE = ego_bih[jg] + ego_bhh[jg];

    // ---- one-time staging: lane K/V (constant), h=0, mask ----
    for (int i = tid; i < 64 * 128; i += 1024) {
        int r = i >> 7, c = i & 127;
        float kvv = lane_kb[((size_t)b * KVN + 32 + r) * F + c];
        float vvv = lane_vb[((size_t)b * KVN + 32 + r) * F + c];
        Kbuf[(32 + r) * 129 + c] = kvv;
        VtF[c * 100 + 32 + r]    = vvv;
    }
    for (int i = tid; i < 32 * 128; i += 1024) hsS[i] = 0.f;
    if (tid < 96) mkS[tid] = (tid < 32) ? mask_input[b * 32 + tid] : lane_mask[b * 64 + tid - 32];
    __syncthreads();

    const float3* W3 = (const float3*)wqkv3;
    const float4* W9 = (const float4*)vehW9;

#pragma unroll 1
    for (int step = 0; step < HH + LEN; ++step) {
        const int mode = (step >= HH) ? 1 : 0;
        const int t = mode ? 0 : step;

        // prefetch wqkv3 chunk 0 (lands during P1)
        float3 rq = W3[tid];

        // ---- P1: build tokens ----
        for (int i = tid; i < 32 * 128; i += 1024) {
            int n = i >> 7, c = i & 127;
            float acc;
            if (mode == 0) {
                acc = conv_b[c];
#pragma unroll
                for (int kt = 0; kt < 3; ++kt) {
                    const float* ip = input + ((size_t)((t + kt) * B + b) * N1 + n) * 2;
                    acc += ip[0] * conv_w[(c * 2 + 0) * 3 + kt] + ip[1] * conv_w[(c * 2 + 1) * 3 + kt];
                }
                const float* hp = hist_pos + ((size_t)(t * B + b) * N1 + n) * 2;
                acc += hp[0] * pos_w[c] + hp[1] * pos_w[128 + c] + pos_b[c];
            } else {
                const float* pp = pred_pos + (size_t)b * 384 + n * 12;
                float mx = 0.f, my = 0.f;
#pragma unroll
                for (int p = 0; p < 6; ++p) { mx += pp[p * 2]; my += pp[p * 2 + 1]; }
                mx *= (1.f / 6.f); my *= (1.f / 6.f);
                acc = hsS[i] + mx * pos_w[c] + my * pos_w[128 + c] + pos_b[c];
            }
            tokS[i] = acc;
        }
        __syncthreads();

        // ---- P2: q/k/v projections, wqkv3 streamed through LDS dbuf ----
        {
            ((float3*)Kbuf)[tid] = rq;            // chunk 0 -> bufA
            rq = W3[1024 + tid];                  // prefetch chunk 1
            __syncthreads();

            float aq[4] = {0, 0, 0, 0}, ak[4] = {0, 0, 0, 0}, av[4] = {0, 0, 0, 0};
#pragma unroll 1
            for (int c = 0; c < 16; ++c) {
                if (c < 15) { float* bo = (c & 1) ? Kbuf : scF; ((float3*)bo)[tid] = rq; }
                if (c < 14) rq = W3[(size_t)(c + 2) * 1024 + tid];
                const float3* bw = (const float3*)((c & 1) ? scF : Kbuf);
                const int K0 = c * 8;
#pragma unroll
                for (int q4 = 0; q4 < 2; ++q4) {
                    const int k2 = K0 + q4 * 4;
                    float4 xv[4];
#pragma unroll
                    for (int r = 0; r < 4; ++r) xv[r] = *(const float4*)&tokS[(n0 + r) * 128 + k2];
#pragma unroll
                    for (int kk = 0; kk < 4; ++kk) {
                        float3 w3 = bw[(q4 * 4 + kk) * 128 + f];
#pragma unroll
                        for (int r = 0; r < 4; ++r) {
                            float x = (&xv[r].x)[kk];
                            aq[r] += x * w3.x; ak[r] += x * w3.y; av[r] += x * w3.z;
                        }
                    }
                }
                __syncthreads();
            }
#pragma unroll
            for (int r = 0; r < 4; ++r) {
                qsS[(n0 + r) * 128 + f]  = aq[r];
                Kbuf[(n0 + r) * 129 + f] = ak[r];
                VtF[f * 100 + n0 + r]    = av[r];
            }
        }
        __syncthreads();

        // ---- attention, heads sequential ----
#pragma unroll 1
        for (int h = 0; h < NH; ++h) {
            const int hb = h * 16;
            {
                const int lane = tid & 63;
                const int rb = (tid >> 6) * 2;
                const bool k2ok = lane < 32;
                float s0[2] = {0, 0}, s1[2] = {0, 0};
                for (int d4 = 0; d4 < 16; d4 += 4) {
                    float4 qv0 = *(const float4*)&qsS[rb * 128 + hb + d4];
                    float4 qv1 = *(const float4*)&qsS[(rb + 1) * 128 + hb + d4];
#pragma unroll
                    for (int kk = 0; kk < 4; ++kk) {
                        float kA = Kbuf[lane * 129 + hb + d4 + kk];
                        float kB = k2ok ? Kbuf[(64 + lane) * 129 + hb + d4 + kk] : 0.f;
                        float q0 = (&qv0.x)[kk], q1 = (&qv1.x)[kk];
                        s0[0] += q0 * kA; s0[1] += q1 * kA;
                        s1[0] += q0 * kB; s1[1] += q1 * kB;
                    }
                }
                float mA = mkS[lane];
                float mB = k2ok ? mkS[64 + lane] : 0.f;
#pragma unroll
                for (int r = 0; r < 2; ++r) {
                    float v0 = (mA > 0.f) ? s0[r] * 0.25f : -1e9f;
                    float v1 = (k2ok && mB > 0.f) ? s1[r] * 0.25f : -1e9f;
                    float mx = fmaxf(v0, v1);
#pragma unroll
                    for (int off = 32; off; off >>= 1) mx = fmaxf(mx, __shfl_xor(mx, off));
                    float e0 = __expf(v0 - mx);
                    float e1 = k2ok ? __expf(v1 - mx) : 0.f;
                    float s = e0 + e1;
#pragma unroll
                    for (int off = 32; off; off >>= 1) s += __shfl_xor(s, off);
                    float inv = 1.f / s;
                    scF[(rb + r) * 96 + lane] = e0 * inv;
                    if (k2ok) scF[(rb + r) * 96 + 64 + lane] = e1 * inv;
                }
            }
            __syncthreads();
            {
                const int pv = tid >> 1, half = tid & 1;
                const int qr = pv >> 4, d = pv & 15;
                const float4* vrow = Vt4 + (hb + d) * 25 + half * 12;
                const float4* srow = sc4 + qr * 24 + half * 12;
                float acc = 0.f;
#pragma unroll
                for (int q4 = 0; q4 < 12; ++q4) {
                    float4 pf = srow[q4], vv = vrow[q4];
                    acc += pf.x * vv.x + pf.y * vv.y + pf.z * vv.z + pf.w * vv.w;
                }
                acc += __shfl_xor(acc, 1);
                if (!half) qsS[qr * 128 + hb + d] = acc;
            }
            __syncthreads();
        }

        // ---- proj + residual (into tokS); wo read directly ----
        {
            float ac[4] = {0, 0, 0, 0};
#pragma unroll 2
            for (int k2 = 0; k2 < 128; k2 += 4) {
                float4 av4[4];
#pragma unroll
                for (int r = 0; r < 4; ++r) av4[r] = *(const float4*)&qsS[(n0 + r) * 128 + k2];
#pragma unroll
                for (int kk = 0; kk < 4; ++kk) {
                    float w = wo[(size_t)(k2 + kk) * 128 + f];
#pragma unroll
                    for (int r = 0; r < 4; ++r) ac[r] += (&av4[r].x)[kk] * w;
                }
            }
#pragma unroll
            for (int r = 0; r < 4; ++r) tokS[(n0 + r) * 128 + f] += ac[r];
        }
        __syncthreads();

        // ---- LayerNorm in place ----
        {
            const int row = tid >> 5, l = tid & 31;
            float x0 = tokS[row * 128 + l],      x1 = tokS[row * 128 + l + 32];
            float x2 = tokS[row * 128 + l + 64], x3 = tokS[row * 128 + l + 96];
            float s1v = x0 + x1 + x2 + x3;
            float s2v = x0 * x0 + x1 * x1 + x2 * x2 + x3 * x3;
#pragma unroll
            for (int off = 16; off; off >>= 1) {
                s1v += __shfl_xor(s1v, off, 32);
                s2v += __shfl_xor(s2v, off, 32);
            }
            float mean = s1v * (1.f / 128.f);
            float rs = rsqrtf(s2v * (1.f / 128.f) - mean * mean + 1e-5f);
            const float* gg = (row == 0) ? ln_ego_g : ln_g;
            const float* bb = (row == 0) ? ln_ego_b : ln_b;
            tokS[row * 128 + l]      = (x0 - mean) * rs * gg[l]      + bb[l];
            tokS[row * 128 + l + 32] = (x1 - mean) * rs * gg[l + 32] + bb[l + 32];
            tokS[row * 128 + l + 64] = (x2 - mean) * rs * gg[l + 64] + bb[l + 64];
            tokS[row * 128 + l + 96] = (x3 - mean) * rs * gg[l + 96] + bb[l + 96];
        }
        __syncthreads();

        // ---- LSTM cell: vehW9 streamed through LDS dbuf; ego gate-parallel ----
        {
            float4 rv = W9[tid];     // chunk 0 prefetch (lands under ego compute)

            float cold[4];
            const size_t cbase = ((size_t)b * 32 + n0) * 128 + f;
#pragma unroll
            for (int r = 0; r < 4; ++r) cold[r] = cbuf[cbase + (size_t)r * 128];

            // ego gates (agent 0), all 1024 threads
            {
                float accE = kh ? 0.f : bsumE;
                for (int k4 = kh * 16; k4 < kh * 16 + 16; ++k4) {
                    const float4* wp = (const float4*)&egoP2[(size_t)(k4 * 512 + jg) * 8];
                    float4 wi = wp[0], wh = wp[1];
                    float4 xv = *(const float4*)&tokS[k4 * 4];
                    float4 hv = *(const float4*)&hsS[k4 * 4];
                    accE += xv.x * wi.x + xv.y * wi.y + xv.z * wi.z + xv.w * wi.w
                          + hv.x * wh.x + hv.y * wh.y + hv.z * wh.z + hv.w * wh.w;
                }
                accE += __shfl_xor(accE, 1);
                if (!kh) scF[jg] = accE;
            }

            ((float4*)Kbuf)[tid] = rv;            // chunk 0 -> bufA
            rv = W9[1024 + tid];                  // prefetch chunk 1
            __syncthreads();                      // bufA + scF(ego) visible

            float acc[4][4];
#pragma unroll
            for (int r = 0; r < 4; ++r)
#pragma unroll
                for (int g = 0; g < 4; ++g) acc[r][g] = bv[g];

#pragma unroll 1
            for (int c = 0; c < 32; ++c) {
                if (c < 31) { float* bo = (c & 1) ? Kbuf : qsS; ((float4*)bo)[tid] = rv; }
                if (c < 30) rv = W9[(size_t)(c + 2) * 1024 + tid];
                const float4* bw = (const float4*)((c & 1) ? qsS : Kbuf);
                const int K0 = c * 4;
                float4 xv[4], hv[4];
#pragma unroll
                for (int r = 0; r < 4; ++r) {
                    xv[r] = *(const float4*)&tokS[(n0 + r) * 128 + K0];
                    hv[r] = *(const float4*)&hsS[(n0 + r) * 128 + K0];
                }
#pragma unroll
                for (int kk = 0; kk < 4; ++kk) {
                    float4 wi = bw[kk * 256 + f];
                    float4 wh = bw[kk * 256 + 128 + f];
#pragma unroll
                    for (int r = 0; r < 4; ++r) {
                        float x = (&xv[r].x)[kk], hc = (&hv[r].x)[kk];
                        acc[r][0] += x * wi.x + hc * wh.x;
                        acc[r][1] += x * wi.y + hc * wh.y;
                        acc[r][2] += x * wi.z + hc * wh.z;
                        acc[r][3] += x * wi.w + hc * wh.w;
                    }
                }
                __syncthreads();
            }

#pragma unroll
            for (int r = 0; r < 4; ++r) {
                float gi = acc[r][0], gf = acc[r][1], gg = acc[r][2], go = acc[r][3];
                if (r == 0 && ng == 0) {   // agent 0 -> ego gates from scF
                    gi = scF[f]; gf = scF[128 + f]; gg = scF[256 + f]; go = scF[384 + f];
                }
                float c2 = fsigmoid(gf) * cold[r] + fsigmoid(gi) * ftanh(gg);
                float h2 = fsigmoid(go) * ftanh(c2);
                cbuf[cbase + (size_t)r * 128] = c2;
                hsS[(n0 + r) * 128 + f] = h2;
            }
        }

        // ---- prediction head + pos update + y ----
        if (mode) {
            __syncthreads();   // h2 visible; scF (ego gates) consumed
            if (tid < 288) {
                int jj = tid % 36, g = tid / 36;
                const float* Wv = &oWT[(size_t)(36 + jj) * 128];
                const float* We = &oWT[(size_t)jj * 128];
                float a[4];
                float aE = out_ego_b[jj];
#pragma unroll
                for (int r = 0; r < 4; ++r) a[r] = out_b[jj];
                for (int k2 = 0; k2 < 128; k2 += 4) {
                    float4 wv4 = *(const float4*)&Wv[k2];
#pragma unroll
                    for (int r = 0; r < 4; ++r) {
                        float4 hv = *(const float4*)&hsS[(g * 4 + r) * 128 + k2];
                        a[r] += hv.x * wv4.x + hv.y * wv4.y + hv.z * wv4.z + hv.w * wv4.w;
                    }
                    if (g == 0) {
                        float4 we4 = *(const float4*)&We[k2];
                        float4 hv0 = *(const float4*)&hsS[k2];
                        aE += hv0.x * we4.x + hv0.y * we4.y + hv0.z * we4.z + hv0.w * we4.w;
                    }
                }
                if (g == 0) a[0] = aE;
#pragma unroll
                for (int r = 0; r < 4; ++r) scF[(g * 4 + r) * 36 + jj] = a[r];
            }
            __syncthreads();
            if (tid < 192) {
                int n = tid / 6, p = tid - n * 6;
                float dl = scF[n * 36 + p * 6], yaw = scF[n * 36 + p * 6 + 1];
                float* pp = pred_pos + (size_t)b * 384 + n * 12 + p * 2;
                float px = pp[0] + dl * cosf(yaw);
                float py = pp[1] + dl * sinf(yaw);
                pp[0] = px; pp[1] = py;
                float* y = out + (size_t)(step - HH) * (B * N1 * P6) + ((size_t)b * 32 + n) * 36 + p * 6;
                y[0] = px; y[1] = py;
                y[2] = scF[n * 36 + p * 6 + 2]; y[3] = scF[n * 36 + p * 6 + 3];
                y[4] = scF[n * 36 + p * 6 + 4]; y[5] = scF[n * 36 + p * 6 + 5];
            }
        }
        __syncthreads();   // h, pred_pos ready for next step
    }
}

// ---------------- launcher ----------------
extern "C" void kernel_launch(void* const* d_in, const int* in_sizes, int n_in,
                              void* d_out, int out_size, void* d_ws, size_t ws_size,
                              hipStream_t stream) {
    const float* input      = (const float*)d_in[0];
    const float* init_pos   = (const float*)d_in[1];
    const float* lane_input = (const float*)d_in[2];
    const float* mask_input = (const float*)d_in[3];
    const float* lane_mask  = (const float*)d_in[4];
    const float* conv_w     = (const float*)d_in[5];
    const float* conv_b     = (const float*)d_in[6];
    const float* pos_w      = (const float*)d_in[7];
    const float* pos_b      = (const float*)d_in[8];
    const float* lane_w1    = (const float*)d_in[9];
    const float* lane_b1    = (const float*)d_in[10];
    const float* lane_w2    = (const float*)d_in[11];
    const float* lane_b2    = (const float*)d_in[12];
    const float* lane_to_f  = (const float*)d_in[13];
    const float* wq         = (const float*)d_in[14];
    const float* wk         = (const float*)d_in[15];
    const float* wv         = (const float*)d_in[16];
    const float* wo         = (const float*)d_in[17];
    const float* ln_ego_g   = (const float*)d_in[18];
    const float* ln_ego_b   = (const float*)d_in[19];
    const float* ln_g       = (const float*)d_in[20];
    const float* ln_b       = (const float*)d_in[21];
    const float* ego_wih    = (const float*)d_in[22];
    const float* ego_whh    = (const float*)d_in[23];
    const float* ego_bih    = (const float*)d_in[24];
    const float* ego_bhh    = (const float*)d_in[25];
    const float* veh_wih    = (const float*)d_in[26];
    const float* veh_whh    = (const float*)d_in[27];
    const float* veh_bih    = (const float*)d_in[28];
    const float* veh_bhh    = (const float*)d_in[29];
    const float* out_ego_w  = (const float*)d_in[30];
    const float* out_ego_b  = (const float*)d_in[31];
    const float* out_w      = (const float*)d_in[32];
    const float* out_b      = (const float*)d_in[33];

    float* out = (float*)d_out;
    float* ws = (float*)d_ws;

    // workspace layout (floats)
    float* kv       = ws;                                   // B*KVN*F
    float* kb       = kv + (size_t)B * KVN * F;             // B*KVN*F (lane rows used)
    float* vb       = kb + (size_t)B * KVN * F;             // B*KVN*F
    float* cbuf     = vb + (size_t)B * KVN * F;             // B*N1*F
    float* hist_pos = cbuf + (size_t)B * N1 * F;            // HH*B*N1*2
    float* pred_pos = hist_pos + (size_t)HH * B * N1 * 2;   // B*N1*NP*2
    float* vehW9    = pred_pos + (size_t)B * N1 * NP * 2;   // 128*128*8
    float* egoP2    = vehW9 + (size_t)128 * 128 * 8;        // 32*512*8
    float* wqkv3    = egoP2 + (size_t)32 * 512 * 8;         // 128*128*3
    float* oWT      = wqkv3 + (size_t)128 * 128 * 3;        // 2*36*128

    hipMemsetAsync(cbuf, 0, (size_t)B * N1 * F * sizeof(float), stream);
    k_lane_tok<<<B * L, 64, 0, stream>>>(lane_input, lane_w1, lane_b1, lane_w2, lane_b2,
                                         lane_to_f, kv);
    k_hist_pos<<<(B * N1 + 255) / 256, 256, 0, stream>>>(input, init_pos, hist_pos, pred_pos);
    k_build_w9<<<(128 * 128 * 8 + 255) / 256, 256, 0, stream>>>(veh_wih, veh_whh, vehW9);
    k_build_egoP<<<(32 * 512 * 8 + 255) / 256, 256, 0, stream>>>(ego_wih, ego_whh, egoP2);
    k_build_wqkv3<<<(128 * 128 + 255) / 256, 256, 0, stream>>>(wq, wk, wv, wqkv3);
    k_build_oWT<<<(2 * 36 * 128 + 255) / 256, 256, 0, stream>>>(out_ego_w, out_w, oWT);
    k_lane_kv<<<B * 8, 256, 0, stream>>>(kv, wk, wv, kb, vb);

    k_mega<<<B, 1024, 0, stream>>>(input, hist_pos, conv_w, conv_b, pos_w, pos_b,
                                   wqkv3, wo,
                                   ln_ego_g, ln_ego_b, ln_g, ln_b,
                                   egoP2, vehW9, ego_bih, ego_bhh, veh_bih, veh_bhh,
                                   oWT, out_ego_b, out_b,
                                   mask_input, lane_mask, kb, vb, pred_pos, cbuf, out);
}

// Round 4
// 9608.636 us; speedup vs baseline: 1.1663x; 1.1663x over previous
//
#include <hip/hip_runtime.h>
#include <hip/hip_bf16.h>
#include <math.h>

// ---------------- constants (fixed by setup_inputs) ----------------
constexpr int B   = 128;   // batch
constexpr int N1  = 32;    // agents (1 ego + 31 veh)
constexpr int HH  = 20;    // history steps (T-2)
constexpr int L   = 64;    // lanes
constexpr int PTS = 10;    // points per lane
constexpr int F   = 128;   // feature size
constexpr int LF  = 64;    // lane feature
constexpr int NH  = 8;     // heads
constexpr int HD  = 16;    // head dim
constexpr int KVN = 96;    // kv tokens = 32 agents + 64 lanes
constexpr int G4  = 512;   // 4*F lstm gates
constexpr int NP  = 6;     // num preds
constexpr int P6  = 36;    // NP*6
constexpr int LEN = 30;    // len_pred

__device__ __forceinline__ float fsigmoid(float x) { return 1.f / (1.f + __expf(-x)); }
__device__ __forceinline__ float ftanh(float x)    { return 1.f - 2.f / (__expf(2.f * x) + 1.f); }

// ---------------- one-time kernels ----------------

__global__ void k_lane_tok(const float* __restrict__ lane_input,
                           const float* __restrict__ w1, const float* __restrict__ b1,
                           const float* __restrict__ w2, const float* __restrict__ b2,
                           const float* __restrict__ to_f,
                           float* __restrict__ kvbuf) {
    int bl = blockIdx.x; int b = bl / L, l = bl % L;
    int tid = threadIdx.x; // 64 threads
    __shared__ float h1[LF][16];
    __shared__ float m[LF];
    const float* xin = lane_input + ((size_t)(b * L + l) * PTS) * 2;
    float w10 = w1[tid], w11 = w1[LF + tid], bb1 = b1[tid];
#pragma unroll
    for (int p = 0; p < PTS; ++p) {
        float v = xin[p * 2] * w10 + xin[p * 2 + 1] * w11 + bb1;
        h1[tid][p] = fmaxf(v, 0.f);
    }
    __syncthreads();
    float ap[PTS];
    float bb2 = b2[tid];
#pragma unroll
    for (int p = 0; p < PTS; ++p) ap[p] = bb2;
    for (int h = 0; h < LF; ++h) {
        float w2v = w2[h * LF + tid];
        float4 x0 = *(const float4*)&h1[h][0];
        float4 x1 = *(const float4*)&h1[h][4];
        float2 x2 = *(const float2*)&h1[h][8];
        ap[0] += x0.x * w2v; ap[1] += x0.y * w2v; ap[2] += x0.z * w2v; ap[3] += x0.w * w2v;
        ap[4] += x1.x * w2v; ap[5] += x1.y * w2v; ap[6] += x1.z * w2v; ap[7] += x1.w * w2v;
        ap[8] += x2.x * w2v; ap[9] += x2.y * w2v;
    }
    float acc = 0.f;
#pragma unroll
    for (int p = 0; p < PTS; ++p) acc += fmaxf(ap[p], 0.f);
    m[tid] = acc * (1.f / PTS);
    __syncthreads();
    float* outp = kvbuf + ((size_t)(b * KVN) + 32 + l) * F;
    for (int f = tid; f < F; f += LF) {
        float s = 0.f;
        for (int j = 0; j < LF; ++j) s += m[j] * to_f[j * F + f];
        outp[f] = s;
    }
}

__global__ void k_lane_kv(const float* __restrict__ kvbuf,
                          const float* __restrict__ wk, const float* __restrict__ wv,
                          float* __restrict__ kb, float* __restrict__ vb) {
    int g = blockIdx.x & 7, b = blockIdx.x >> 3;
    int n0 = 32 + g * 8;
    int tid = threadIdx.x; // 256
    int j = tid & 127, rh = tid >> 7;
    __shared__ float tok[8][F];
    for (int i = tid; i < 8 * F; i += 256) {
        int r = i >> 7, c = i & 127;
        tok[r][c] = kvbuf[((size_t)b * KVN + n0 + r) * F + c];
    }
    __syncthreads();
    float ak[4] = {0, 0, 0, 0}, av[4] = {0, 0, 0, 0};
    int r0 = rh * 4;
    for (int k2 = 0; k2 < F; ++k2) {
        float wkv = wk[k2 * F + j], wvv = wv[k2 * F + j];
#pragma unroll
        for (int r = 0; r < 4; ++r) {
            float x = tok[r0 + r][k2];
            ak[r] += x * wkv; av[r] += x * wvv;
        }
    }
#pragma unroll
    for (int r = 0; r < 4; ++r) {
        int n = n0 + r0 + r;
        kb[((size_t)b * KVN + n) * F + j] = ak[r];
        vb[((size_t)b * KVN + n) * F + j] = av[r];
    }
}

__global__ void k_hist_pos(const float* __restrict__ input,
                           const float* __restrict__ init_pos,
                           float* __restrict__ hist_pos,
                           float* __restrict__ pred_pos) {
    int idx = blockIdx.x * blockDim.x + threadIdx.x;
    if (idx >= B * N1) return;
    float px = init_pos[idx * 2], py = init_pos[idx * 2 + 1];
    int b = idx / N1, n = idx % N1;
    for (int t = 0; t < HH; ++t) {
        const float* ip = input + ((size_t)(t * B + b) * N1 + n) * 2;
        float dl = ip[0], yaw = ip[1];
        px += dl * cosf(yaw);
        py += dl * sinf(yaw);
        float* hp = hist_pos + ((size_t)(t * B + b) * N1 + n) * 2;
        hp[0] = px; hp[1] = py;
    }
#pragma unroll
    for (int p = 0; p < NP; ++p) {
        pred_pos[((size_t)idx * NP + p) * 2 + 0] = px;
        pred_pos[((size_t)idx * NP + p) * 2 + 1] = py;
    }
}

// veh LSTM weights: vehW9[(((k*2 + part)*128 + f)*4 + g)] = (part?whh:wih)[(g*128+f)*128 + k]
__global__ void k_build_w9(const float* __restrict__ wih, const float* __restrict__ whh,
                           float* __restrict__ w9) {
    int i = blockIdx.x * blockDim.x + threadIdx.x;
    if (i >= 128 * 128 * 8) return;
    int g = i & 3, f = (i >> 2) & 127, part = (i >> 9) & 1, k = i >> 10;
    const float* src = part ? whh : wih;
    w9[i] = src[((size_t)(g * 128 + f)) * 128 + k];
}

// ego LSTM weights gate-parallel: egoP[((k4*512 + j)*2 + s)*4 + kk] = W_s[j][k4*4+kk]
__global__ void k_build_egoP(const float* __restrict__ wih, const float* __restrict__ whh,
                             float* __restrict__ egoP) {
    int i = blockIdx.x * blockDim.x + threadIdx.x;
    if (i >= 32 * 512 * 8) return;
    int kk = i & 3, s = (i >> 2) & 1, j = (i >> 3) & 511, k4 = i >> 12;
    int k = k4 * 4 + kk;
    egoP[i] = (s == 0) ? wih[(size_t)j * 128 + k] : whh[(size_t)j * 128 + k];
}

// fuse wq/wk/wv/wo into one float4 per (k,j)
__global__ void k_build_wqkvo(const float* __restrict__ wq, const float* __restrict__ wk,
                              const float* __restrict__ wv, const float* __restrict__ wo,
                              float4* __restrict__ out4) {
    int i = blockIdx.x * blockDim.x + threadIdx.x;
    if (i >= 128 * 128) return;
    out4[i] = make_float4(wq[i], wk[i], wv[i], wo[i]);
}

// transposed output-head weights: oWT[(m*36+jj)*128 + k] = W_m[k*36+jj]
__global__ void k_build_oWT(const float* __restrict__ oe_w, const float* __restrict__ ov_w,
                            float* __restrict__ oWT) {
    int i = blockIdx.x * blockDim.x + threadIdx.x;
    if (i >= 2 * 36 * 128) return;
    int m = i / 4608, r = i % 4608, jj = r >> 7, k = r & 127;
    oWT[i] = (m == 0) ? oe_w[(size_t)k * 36 + jj] : ov_w[(size_t)k * 36 + jj];
}

// ---------------- persistent per-batch mega kernel ----------------
// LDS: Kbuf 49536 + Vt 51200 + tok 16384 + qs 16384 + hs 16384 + sc 12288 + mk 384 = 162560 B
// Weight-redundancy is cut via lane-bit-5 work splits + shfl_xor(.,32) butterflies:
//   QKV : lane>>5 = k-half      (wqkvo reads 2KB -> 1KB /thread)
//   proj: lane>>5 = k-half      (wo    reads 512B -> 256B)
//   LSTM: lane>>5 = part (x|h)  (vehW9 reads 4KB -> 2KB)
__global__ __launch_bounds__(1024, 1) void k_mega(
    const float* __restrict__ input, const float* __restrict__ hist_pos,
    const float* __restrict__ conv_w, const float* __restrict__ conv_b,
    const float* __restrict__ pos_w, const float* __restrict__ pos_b,
    const float4* __restrict__ wqkvo, const float* __restrict__ wo,
    const float* __restrict__ ln_ego_g, const float* __restrict__ ln_ego_b,
    const float* __restrict__ ln_g, const float* __restrict__ ln_b,
    const float* __restrict__ egoP2, const float* __restrict__ vehW9,
    const float* __restrict__ ego_bih, const float* __restrict__ ego_bhh,
    const float* __restrict__ veh_bih, const float* __restrict__ veh_bhh,
    const float* __restrict__ oWT,
    const float* __restrict__ out_ego_b, const float* __restrict__ out_b,
    const float* __restrict__ mask_input, const float* __restrict__ lane_mask,
    const float* __restrict__ lane_kb, const float* __restrict__ lane_vb,
    float* __restrict__ pred_pos, float* __restrict__ cbuf,
    float* __restrict__ out)
{
    const int b = blockIdx.x;
    const int tid = threadIdx.x;

    __shared__ float  Kbuf[96 * 129];   // K[kvrow][feat], pad 129 (conflict-free b32)
    __shared__ float4 Vt4[128 * 25];    // V^T[feat][kvrow], stride 100 floats
    __shared__ float  tokS[32 * 128];   // tokens -> residual -> x (LN'd)
    __shared__ float  qsS[32 * 128];    // q, then attention output
    __shared__ float  hsS[32 * 128];    // LSTM h, persistent
    __shared__ float4 sc4[32 * 24];     // probs [32][96]; ego-gate / o36 scratch
    __shared__ float  mkS[96];

    float* VtF = (float*)Vt4;
    float* scF = (float*)sc4;

    // split-phase indexing: lane bit 5 = part/k-half
    const int lane = tid & 63, wid = tid >> 6;
    const int fl  = lane & 31, part = lane >> 5;
    const int oct = wid >> 2;                 // 4 octs of 8 agents
    const int fW  = (wid & 3) * 32 + fl;      // feature owned in split phases
    const int nOct = oct * 8;

    // ego gate-parallel indexing
    const int jg = tid >> 1;      // gate 0..511
    const int kh = tid & 1;       // k-half

    // veh bias (gates 0..3 at fW), added by part0 only
    float4 bv4;
    bv4.x = veh_bih[0 * 128 + fW] + veh_bhh[0 * 128 + fW];
    bv4.y = veh_bih[1 * 128 + fW] + veh_bhh[1 * 128 + fW];
    bv4.z = veh_bih[2 * 128 + fW] + veh_bhh[2 * 128 + fW];
    bv4.w = veh_bih[3 * 128 + fW] + veh_bhh[3 * 128 + fW];
    const float bsumE = ego_bih[jg] + ego_bhh[jg];

    // ---- one-time staging: lane K/V (constant), h=0, mask ----
    for (int i = tid; i < 64 * 128; i += 1024) {
        int r = i >> 7, c = i & 127;
        Kbuf[(32 + r) * 129 + c] = lane_kb[((size_t)b * KVN + 32 + r) * F + c];
        VtF[c * 100 + 32 + r]    = lane_vb[((size_t)b * KVN + 32 + r) * F + c];
    }
    for (int i = tid; i < 32 * 128; i += 1024) hsS[i] = 0.f;
    if (tid < 96) mkS[tid] = (tid < 32) ? mask_input[b * 32 + tid] : lane_mask[b * 64 + tid - 32];
    __syncthreads();

#pragma unroll 1
    for (int step = 0; step < HH + LEN; ++step) {
        const int mode = (step >= HH) ? 1 : 0;
        const int t = mode ? 0 : step;

        // ---- P1: build tokens ----
        for (int i = tid; i < 32 * 128; i += 1024) {
            int n = i >> 7, c = i & 127;
            float acc;
            if (mode == 0) {
                acc = conv_b[c];
#pragma unroll
                for (int kt = 0; kt < 3; ++kt) {
                    const float* ip = input + ((size_t)((t + kt) * B + b) * N1 + n) * 2;
                    acc += ip[0] * conv_w[(c * 2 + 0) * 3 + kt] + ip[1] * conv_w[(c * 2 + 1) * 3 + kt];
                }
                const float* hp = hist_pos + ((size_t)(t * B + b) * N1 + n) * 2;
                acc += hp[0] * pos_w[c] + hp[1] * pos_w[128 + c] + pos_b[c];
            } else {
                const float* pp = pred_pos + (size_t)b * 384 + n * 12;
                float mx = 0.f, my = 0.f;
#pragma unroll
                for (int p = 0; p < 6; ++p) { mx += pp[p * 2]; my += pp[p * 2 + 1]; }
                mx *= (1.f / 6.f); my *= (1.f / 6.f);
                acc = hsS[i] + mx * pos_w[c] + my * pos_w[128 + c] + pos_b[c];
            }
            tokS[i] = acc;
        }
        __syncthreads();

        // ---- P2: q/k/v projections; k-half split across lane halves ----
        {
            float aq[8], ak[8], av[8];
#pragma unroll
            for (int a = 0; a < 8; ++a) { aq[a] = 0.f; ak[a] = 0.f; av[a] = 0.f; }
            const int k0 = part * 64;
#pragma unroll 4
            for (int k = 0; k < 64; ++k) {
                float4 w4 = wqkvo[(size_t)(k0 + k) * 128 + fW];
#pragma unroll
                for (int a = 0; a < 8; ++a) {
                    float x = tokS[(nOct + a) * 128 + k0 + k];   // broadcast read
                    aq[a] += x * w4.x; ak[a] += x * w4.y; av[a] += x * w4.z;
                }
            }
#pragma unroll
            for (int a = 0; a < 8; ++a) {
                aq[a] += __shfl_xor(aq[a], 32);
                ak[a] += __shfl_xor(ak[a], 32);
                av[a] += __shfl_xor(av[a], 32);
            }
            const int a0 = part * 4;
#pragma unroll
            for (int aa = 0; aa < 4; ++aa) {
                int n = nOct + a0 + aa;
                qsS[n * 128 + fW]  = aq[a0 + aa];
                Kbuf[n * 129 + fW] = ak[a0 + aa];
                VtF[fW * 100 + n]  = av[a0 + aa];
            }
        }
        __syncthreads();

        // ---- attention, heads sequential ----
#pragma unroll 1
        for (int h = 0; h < NH; ++h) {
            const int hb = h * 16;
            {
                const int rb = (tid >> 6) * 2;
                const bool k2ok = lane < 32;
                float s0[2] = {0, 0}, s1[2] = {0, 0};
                for (int d4 = 0; d4 < 16; d4 += 4) {
                    float4 qv0 = *(const float4*)&qsS[rb * 128 + hb + d4];
                    float4 qv1 = *(const float4*)&qsS[(rb + 1) * 128 + hb + d4];
#pragma unroll
                    for (int kk = 0; kk < 4; ++kk) {
                        float kA = Kbuf[lane * 129 + hb + d4 + kk];
                        float kB = k2ok ? Kbuf[(64 + lane) * 129 + hb + d4 + kk] : 0.f;
                        float q0 = (&qv0.x)[kk], q1 = (&qv1.x)[kk];
                        s0[0] += q0 * kA; s0[1] += q1 * kA;
                        s1[0] += q0 * kB; s1[1] += q1 * kB;
                    }
                }
                float mA = mkS[lane];
                float mB = k2ok ? mkS[64 + lane] : 0.f;
#pragma unroll
                for (int r = 0; r < 2; ++r) {
                    float v0 = (mA > 0.f) ? s0[r] * 0.25f : -1e9f;
                    float v1 = (k2ok && mB > 0.f) ? s1[r] * 0.25f : -1e9f;
                    float mx = fmaxf(v0, v1);
#pragma unroll
                    for (int off = 32; off; off >>= 1) mx = fmaxf(mx, __shfl_xor(mx, off));
                    float e0 = __expf(v0 - mx);
                    float e1 = k2ok ? __expf(v1 - mx) : 0.f;
                    float s = e0 + e1;
#pragma unroll
                    for (int off = 32; off; off >>= 1) s += __shfl_xor(s, off);
                    float inv = 1.f / s;
                    scF[(rb + r) * 96 + lane] = e0 * inv;
                    if (k2ok) scF[(rb + r) * 96 + 64 + lane] = e1 * inv;
                }
            }
            __syncthreads();
            {
                const int pv = tid >> 1, half = tid & 1;
                const int qr = pv >> 4, d = pv & 15;
                const float4* vrow = Vt4 + (hb + d) * 25 + half * 12;
                const float4* srow = sc4 + qr * 24 + half * 12;
                float acc = 0.f;
#pragma unroll
                for (int q4 = 0; q4 < 12; ++q4) {
                    float4 pf = srow[q4], vv = vrow[q4];
                    acc += pf.x * vv.x + pf.y * vv.y + pf.z * vv.z + pf.w * vv.w;
                }
                acc += __shfl_xor(acc, 1);
                if (!half) qsS[qr * 128 + hb + d] = acc;
            }
            __syncthreads();
        }

        // ---- proj + residual; k-half split ----
        {
            float ao[8];
#pragma unroll
            for (int a = 0; a < 8; ++a) ao[a] = 0.f;
            const int k0 = part * 64;
#pragma unroll 4
            for (int k = 0; k < 64; ++k) {
                float w = wo[(size_t)(k0 + k) * 128 + fW];
#pragma unroll
                for (int a = 0; a < 8; ++a)
                    ao[a] += qsS[(nOct + a) * 128 + k0 + k] * w;   // broadcast read
            }
#pragma unroll
            for (int a = 0; a < 8; ++a) ao[a] += __shfl_xor(ao[a], 32);
            const int a0 = part * 4;
#pragma unroll
            for (int aa = 0; aa < 4; ++aa) {
                int n = nOct + a0 + aa;
                tokS[n * 128 + fW] += ao[a0 + aa];
            }
        }
        __syncthreads();

        // ---- LayerNorm in place ----
        {
            const int row = tid >> 5, l = tid & 31;
            float x0 = tokS[row * 128 + l],      x1 = tokS[row * 128 + l + 32];
            float x2 = tokS[row * 128 + l + 64], x3 = tokS[row * 128 + l + 96];
            float s1v = x0 + x1 + x2 + x3;
            float s2v = x0 * x0 + x1 * x1 + x2 * x2 + x3 * x3;
#pragma unroll
            for (int off = 16; off; off >>= 1) {
                s1v += __shfl_xor(s1v, off, 32);
                s2v += __shfl_xor(s2v, off, 32);
            }
            float mean = s1v * (1.f / 128.f);
            float rs = rsqrtf(s2v * (1.f / 128.f) - mean * mean + 1e-5f);
            const float* gg = (row == 0) ? ln_ego_g : ln_g;
            const float* bb = (row == 0) ? ln_ego_b : ln_b;
            tokS[row * 128 + l]      = (x0 - mean) * rs * gg[l]      + bb[l];
            tokS[row * 128 + l + 32] = (x1 - mean) * rs * gg[l + 32] + bb[l + 32];
            tokS[row * 128 + l + 64] = (x2 - mean) * rs * gg[l + 64] + bb[l + 64];
            tokS[row * 128 + l + 96] = (x3 - mean) * rs * gg[l + 96] + bb[l + 96];
        }
        __syncthreads();

        // ---- LSTM cell ----
        {
            // activation agents for this lane (part0: a 0..3, part1: a 4..7)
            const int a0 = part * 4;
            // c-state preload
            float coldv[4];
#pragma unroll
            for (int aa = 0; aa < 4; ++aa)
                coldv[aa] = cbuf[((size_t)b * 32 + nOct + a0 + aa) * 128 + fW];

            // ego gates (agent 0), gate-parallel across all 1024 threads
            {
                float accE = kh ? 0.f : bsumE;
                for (int k4 = kh * 16; k4 < kh * 16 + 16; ++k4) {
                    const float4* wp = (const float4*)&egoP2[(size_t)(k4 * 512 + jg) * 8];
                    float4 wi = wp[0], wh = wp[1];
                    float4 xv = *(const float4*)&tokS[k4 * 4];
                    float4 hv = *(const float4*)&hsS[k4 * 4];
                    accE += xv.x * wi.x + xv.y * wi.y + xv.z * wi.z + xv.w * wi.w
                          + hv.x * wh.x + hv.y * wh.y + hv.z * wh.z + hv.w * wh.w;
                }
                accE += __shfl_xor(accE, 1);
                if (!kh) scF[jg] = accE;
            }

            // veh gates: part split (x|h) across lane halves; 8 agents per thread
            const float* srcS = part ? hsS : tokS;
            float4 acc[8];
#pragma unroll
            for (int a = 0; a < 8; ++a) acc[a] = part ? make_float4(0.f, 0.f, 0.f, 0.f) : bv4;
#pragma unroll 4
            for (int k = 0; k < 128; ++k) {
                float4 w4 = *(const float4*)&vehW9[((size_t)(k * 2 + part) * 128 + fW) * 4];
#pragma unroll
                for (int a = 0; a < 8; ++a) {
                    float x = srcS[(nOct + a) * 128 + k];   // broadcast read
                    acc[a].x += x * w4.x; acc[a].y += x * w4.y;
                    acc[a].z += x * w4.z; acc[a].w += x * w4.w;
                }
            }
#pragma unroll
            for (int a = 0; a < 8; ++a) {
                acc[a].x += __shfl_xor(acc[a].x, 32);
                acc[a].y += __shfl_xor(acc[a].y, 32);
                acc[a].z += __shfl_xor(acc[a].z, 32);
                acc[a].w += __shfl_xor(acc[a].w, 32);
            }
            __syncthreads();   // tok/hs reads + scF(ego) complete before h overwrite
#pragma unroll
            for (int aa = 0; aa < 4; ++aa) {
                const int a = a0 + aa, n = nOct + a;
                float gi = acc[a].x, gf = acc[a].y, gg = acc[a].z, go = acc[a].w;
                if (oct == 0 && part == 0 && aa == 0) {   // agent 0 -> ego gates
                    gi = scF[fW]; gf = scF[128 + fW]; gg = scF[256 + fW]; go = scF[384 + fW];
                }
                float c2 = fsigmoid(gf) * coldv[aa] + fsigmoid(gi) * ftanh(gg);
                float h2 = fsigmoid(go) * ftanh(c2);
                cbuf[((size_t)b * 32 + n) * 128 + fW] = c2;
                hsS[n * 128 + fW] = h2;
            }
        }

        // ---- prediction head + pos update + y ----
        if (mode) {
            __syncthreads();   // h2 visible; scF (ego gates) consumed
            if (tid < 288) {
                int jj = tid % 36, g = tid / 36;
                const float* Wv = &oWT[(size_t)(36 + jj) * 128];
                const float* We = &oWT[(size_t)jj * 128];
                float a[4];
                float aE = out_ego_b[jj];
#pragma unroll
                for (int r = 0; r < 4; ++r) a[r] = out_b[jj];
                for (int k2 = 0; k2 < 128; k2 += 4) {
                    float4 wv4 = *(const float4*)&Wv[k2];
#pragma unroll
                    for (int r = 0; r < 4; ++r) {
                        float4 hv = *(const float4*)&hsS[(g * 4 + r) * 128 + k2];
                        a[r] += hv.x * wv4.x + hv.y * wv4.y + hv.z * wv4.z + hv.w * wv4.w;
                    }
                    if (g == 0) {
                        float4 we4 = *(const float4*)&We[k2];
                        float4 hv0 = *(const float4*)&hsS[k2];
                        aE += hv0.x * we4.x + hv0.y * we4.y + hv0.z * we4.z + hv0.w * we4.w;
                    }
                }
                if (g == 0) a[0] = aE;
#pragma unroll
                for (int r = 0; r < 4; ++r) scF[(g * 4 + r) * 36 + jj] = a[r];
            }
            __syncthreads();
            if (tid < 192) {
                int n = tid / 6, p = tid - n * 6;
                float dl = scF[n * 36 + p * 6], yaw = scF[n * 36 + p * 6 + 1];
                float* pp = pred_pos + (size_t)b * 384 + n * 12 + p * 2;
                float px = pp[0] + dl * cosf(yaw);
                float py = pp[1] + dl * sinf(yaw);
                pp[0] = px; pp[1] = py;
                float* y = out + (size_t)(step - HH) * (B * N1 * P6) + ((size_t)b * 32 + n) * 36 + p * 6;
                y[0] = px; y[1] = py;
                y[2] = scF[n * 36 + p * 6 + 2]; y[3] = scF[n * 36 + p * 6 + 3];
                y[4] = scF[n * 36 + p * 6 + 4]; y[5] = scF[n * 36 + p * 6 + 5];
            }
        }
        __syncthreads();   // h, pred_pos ready for next step
    }
}

// ---------------- launcher ----------------
extern "C" void kernel_launch(void* const* d_in, const int* in_sizes, int n_in,
                              void* d_out, int out_size, void* d_ws, size_t ws_size,
                              hipStream_t stream) {
    const float* input      = (const float*)d_in[0];
    const float* init_pos   = (const float*)d_in[1];
    const float* lane_input = (const float*)d_in[2];
    const float* mask_input = (const float*)d_in[3];
    const float* lane_mask  = (const float*)d_in[4];
    const float* conv_w     = (const float*)d_in[5];
    const float* conv_b     = (const float*)d_in[6];
    const float* pos_w      = (const float*)d_in[7];
    const float* pos_b      = (const float*)d_in[8];
    const float* lane_w1    = (const float*)d_in[9];
    const float* lane_b1    = (const float*)d_in[10];
    const float* lane_w2    = (const float*)d_in[11];
    const float* lane_b2    = (const float*)d_in[12];
    const float* lane_to_f  = (const float*)d_in[13];
    const float* wq         = (const float*)d_in[14];
    const float* wk         = (const float*)d_in[15];
    const float* wv         = (const float*)d_in[16];
    const float* wo         = (const float*)d_in[17];
    const float* ln_ego_g   = (const float*)d_in[18];
    const float* ln_ego_b   = (const float*)d_in[19];
    const float* ln_g       = (const float*)d_in[20];
    const float* ln_b       = (const float*)d_in[21];
    const float* ego_wih    = (const float*)d_in[22];
    const float* ego_whh    = (const float*)d_in[23];
    const float* ego_bih    = (const float*)d_in[24];
    const float* ego_bhh    = (const float*)d_in[25];
    const float* veh_wih    = (const float*)d_in[26];
    const float* veh_whh    = (const float*)d_in[27];
    const float* veh_bih    = (const float*)d_in[28];
    const float* veh_bhh    = (const float*)d_in[29];
    const float* out_ego_w  = (const float*)d_in[30];
    const float* out_ego_b  = (const float*)d_in[31];
    const float* out_w      = (const float*)d_in[32];
    const float* out_b      = (const float*)d_in[33];

    float* out = (float*)d_out;
    float* ws = (float*)d_ws;

    // workspace layout (floats)
    float* kv       = ws;                                   // B*KVN*F
    float* kb       = kv + (size_t)B * KVN * F;             // B*KVN*F (lane rows used)
    float* vb       = kb + (size_t)B * KVN * F;             // B*KVN*F
    float* cbuf     = vb + (size_t)B * KVN * F;             // B*N1*F
    float* hist_pos = cbuf + (size_t)B * N1 * F;            // HH*B*N1*2
    float* pred_pos = hist_pos + (size_t)HH * B * N1 * 2;   // B*N1*NP*2
    float* vehW9    = pred_pos + (size_t)B * N1 * NP * 2;   // 128*128*8
    float* egoP2    = vehW9 + (size_t)128 * 128 * 8;        // 32*512*8
    float* wqkvo    = egoP2 + (size_t)32 * 512 * 8;         // 128*128*4
    float* oWT      = wqkvo + (size_t)128 * 128 * 4;        // 2*36*128

    hipMemsetAsync(cbuf, 0, (size_t)B * N1 * F * sizeof(float), stream);
    k_lane_tok<<<B * L, 64, 0, stream>>>(lane_input, lane_w1, lane_b1, lane_w2, lane_b2,
                                         lane_to_f, kv);
    k_hist_pos<<<(B * N1 + 255) / 256, 256, 0, stream>>>(input, init_pos, hist_pos, pred_pos);
    k_build_w9<<<(128 * 128 * 8 + 255) / 256, 256, 0, stream>>>(veh_wih, veh_whh, vehW9);
    k_build_egoP<<<(32 * 512 * 8 + 255) / 256, 256, 0, stream>>>(ego_wih, ego_whh, egoP2);
    k_build_wqkvo<<<(128 * 128 + 255) / 256, 256, 0, stream>>>(wq, wk, wv, wo, (float4*)wqkvo);
    k_build_oWT<<<(2 * 36 * 128 + 255) / 256, 256, 0, stream>>>(out_ego_w, out_w, oWT);
    k_lane_kv<<<B * 8, 256, 0, stream>>>(kv, wk, wv, kb, vb);

    k_mega<<<B, 1024, 0, stream>>>(input, hist_pos, conv_w, conv_b, pos_w, pos_b,
                                   (const float4*)wqkvo, wo,
                                   ln_ego_g, ln_ego_b, ln_g, ln_b,
                                   egoP2, vehW9, ego_bih, ego_bhh, veh_bih, veh_bhh,
                                   oWT, out_ego_b, out_b,
                                   mask_input, lane_mask, kb, vb, pred_pos, cbuf, out);
}

// Round 5
// 8938.110 us; speedup vs baseline: 1.2538x; 1.0750x over previous
//
#include <hip/hip_runtime.h>
#include <hip/hip_bf16.h>
#include <math.h>

// ---------------- constants (fixed by setup_inputs) ----------------
constexpr int B   = 128;   // batch
constexpr int N1  = 32;    // agents (1 ego + 31 veh)
constexpr int HH  = 20;    // history steps (T-2)
constexpr int L   = 64;    // lanes
constexpr int PTS = 10;    // points per lane
constexpr int F   = 128;   // feature size
constexpr int LF  = 64;    // lane feature
constexpr int NH  = 8;     // heads
constexpr int HD  = 16;    // head dim
constexpr int KVN = 96;    // kv tokens = 32 agents + 64 lanes
constexpr int G4  = 512;   // 4*F lstm gates
constexpr int NP  = 6;     // num preds
constexpr int P6  = 36;    // NP*6
constexpr int LEN = 30;    // len_pred

__device__ __forceinline__ float fsigmoid(float x) { return 1.f / (1.f + __expf(-x)); }
__device__ __forceinline__ float ftanh(float x)    { return 1.f - 2.f / (__expf(2.f * x) + 1.f); }

// ---------------- one-time kernels ----------------

__global__ void k_lane_tok(const float* __restrict__ lane_input,
                           const float* __restrict__ w1, const float* __restrict__ b1,
                           const float* __restrict__ w2, const float* __restrict__ b2,
                           const float* __restrict__ to_f,
                           float* __restrict__ kvbuf) {
    int bl = blockIdx.x; int b = bl / L, l = bl % L;
    int tid = threadIdx.x; // 64 threads
    __shared__ float h1[LF][16];
    __shared__ float m[LF];
    const float* xin = lane_input + ((size_t)(b * L + l) * PTS) * 2;
    float w10 = w1[tid], w11 = w1[LF + tid], bb1 = b1[tid];
#pragma unroll
    for (int p = 0; p < PTS; ++p) {
        float v = xin[p * 2] * w10 + xin[p * 2 + 1] * w11 + bb1;
        h1[tid][p] = fmaxf(v, 0.f);
    }
    __syncthreads();
    float ap[PTS];
    float bb2 = b2[tid];
#pragma unroll
    for (int p = 0; p < PTS; ++p) ap[p] = bb2;
    for (int h = 0; h < LF; ++h) {
        float w2v = w2[h * LF + tid];
        float4 x0 = *(const float4*)&h1[h][0];
        float4 x1 = *(const float4*)&h1[h][4];
        float2 x2 = *(const float2*)&h1[h][8];
        ap[0] += x0.x * w2v; ap[1] += x0.y * w2v; ap[2] += x0.z * w2v; ap[3] += x0.w * w2v;
        ap[4] += x1.x * w2v; ap[5] += x1.y * w2v; ap[6] += x1.z * w2v; ap[7] += x1.w * w2v;
        ap[8] += x2.x * w2v; ap[9] += x2.y * w2v;
    }
    float acc = 0.f;
#pragma unroll
    for (int p = 0; p < PTS; ++p) acc += fmaxf(ap[p], 0.f);
    m[tid] = acc * (1.f / PTS);
    __syncthreads();
    float* outp = kvbuf + ((size_t)(b * KVN) + 32 + l) * F;
    for (int f = tid; f < F; f += LF) {
        float s = 0.f;
        for (int j = 0; j < LF; ++j) s += m[j] * to_f[j * F + f];
        outp[f] = s;
    }
}

__global__ void k_lane_kv(const float* __restrict__ kvbuf,
                          const float* __restrict__ wk, const float* __restrict__ wv,
                          float* __restrict__ kb, float* __restrict__ vb) {
    int g = blockIdx.x & 7, b = blockIdx.x >> 3;
    int n0 = 32 + g * 8;
    int tid = threadIdx.x; // 256
    int j = tid & 127, rh = tid >> 7;
    __shared__ float tok[8][F];
    for (int i = tid; i < 8 * F; i += 256) {
        int r = i >> 7, c = i & 127;
        tok[r][c] = kvbuf[((size_t)b * KVN + n0 + r) * F + c];
    }
    __syncthreads();
    float ak[4] = {0, 0, 0, 0}, av[4] = {0, 0, 0, 0};
    int r0 = rh * 4;
    for (int k2 = 0; k2 < F; ++k2) {
        float wkv = wk[k2 * F + j], wvv = wv[k2 * F + j];
#pragma unroll
        for (int r = 0; r < 4; ++r) {
            float x = tok[r0 + r][k2];
            ak[r] += x * wkv; av[r] += x * wvv;
        }
    }
#pragma unroll
    for (int r = 0; r < 4; ++r) {
        int n = n0 + r0 + r;
        kb[((size_t)b * KVN + n) * F + j] = ak[r];
        vb[((size_t)b * KVN + n) * F + j] = av[r];
    }
}

__global__ void k_hist_pos(const float* __restrict__ input,
                           const float* __restrict__ init_pos,
                           float* __restrict__ hist_pos,
                           float* __restrict__ pred_pos) {
    int idx = blockIdx.x * blockDim.x + threadIdx.x;
    if (idx >= B * N1) return;
    float px = init_pos[idx * 2], py = init_pos[idx * 2 + 1];
    int b = idx / N1, n = idx % N1;
    for (int t = 0; t < HH; ++t) {
        const float* ip = input + ((size_t)(t * B + b) * N1 + n) * 2;
        float dl = ip[0], yaw = ip[1];
        px += dl * cosf(yaw);
        py += dl * sinf(yaw);
        float* hp = hist_pos + ((size_t)(t * B + b) * N1 + n) * 2;
        hp[0] = px; hp[1] = py;
    }
#pragma unroll
    for (int p = 0; p < NP; ++p) {
        pred_pos[((size_t)idx * NP + p) * 2 + 0] = px;
        pred_pos[((size_t)idx * NP + p) * 2 + 1] = py;
    }
}

// veh LSTM weights: vehW9[(((k*2 + part)*128 + f)*4 + g)] = (part?whh:wih)[(g*128+f)*128 + k]
__global__ void k_build_w9(const float* __restrict__ wih, const float* __restrict__ whh,
                           float* __restrict__ w9) {
    int i = blockIdx.x * blockDim.x + threadIdx.x;
    if (i >= 128 * 128 * 8) return;
    int g = i & 3, f = (i >> 2) & 127, part = (i >> 9) & 1, k = i >> 10;
    const float* src = part ? whh : wih;
    w9[i] = src[((size_t)(g * 128 + f)) * 128 + k];
}

// ego LSTM weights gate-parallel: egoP[((k4*512 + j)*2 + s)*4 + kk] = W_s[j][k4*4+kk]
__global__ void k_build_egoP(const float* __restrict__ wih, const float* __restrict__ whh,
                             float* __restrict__ egoP) {
    int i = blockIdx.x * blockDim.x + threadIdx.x;
    if (i >= 32 * 512 * 8) return;
    int kk = i & 3, s = (i >> 2) & 1, j = (i >> 3) & 511, k4 = i >> 12;
    int k = k4 * 4 + kk;
    egoP[i] = (s == 0) ? wih[(size_t)j * 128 + k] : whh[(size_t)j * 128 + k];
}

// fuse wq/wk/wv/wo into one float4 per (k,j)
__global__ void k_build_wqkvo(const float* __restrict__ wq, const float* __restrict__ wk,
                              const float* __restrict__ wv, const float* __restrict__ wo,
                              float4* __restrict__ out4) {
    int i = blockIdx.x * blockDim.x + threadIdx.x;
    if (i >= 128 * 128) return;
    out4[i] = make_float4(wq[i], wk[i], wv[i], wo[i]);
}

// transposed output-head weights: oWT[(m*36+jj)*128 + k] = W_m[k*36+jj]
__global__ void k_build_oWT(const float* __restrict__ oe_w, const float* __restrict__ ov_w,
                            float* __restrict__ oWT) {
    int i = blockIdx.x * blockDim.x + threadIdx.x;
    if (i >= 2 * 36 * 128) return;
    int m = i / 4608, r = i % 4608, jj = r >> 7, k = r & 127;
    oWT[i] = (m == 0) ? oe_w[(size_t)k * 36 + jj] : ov_w[(size_t)k * 36 + jj];
}

// ---------------- persistent per-batch mega kernel ----------------
// LDS: Kbuf 49536 + Vt 51200 + tok 16384 + qs 16384 + hs 16384 + sc 12288 + mk 384 = 162560 B
// Weight-redundancy cut via lane-bit-5 work splits + shfl_xor(.,32) butterflies.
// RULE #20: every accumulator array is indexed ONLY with compile-time constants;
// the lane-dependent half-selection is done via register select (part ? a[4+i] : a[i]).
__global__ __launch_bounds__(1024, 4) void k_mega(
    const float* __restrict__ input, const float* __restrict__ hist_pos,
    const float* __restrict__ conv_w, const float* __restrict__ conv_b,
    const float* __restrict__ pos_w, const float* __restrict__ pos_b,
    const float4* __restrict__ wqkvo, const float* __restrict__ wo,
    const float* __restrict__ ln_ego_g, const float* __restrict__ ln_ego_b,
    const float* __restrict__ ln_g, const float* __restrict__ ln_b,
    const float* __restrict__ egoP2, const float* __restrict__ vehW9,
    const float* __restrict__ ego_bih, const float* __restrict__ ego_bhh,
    const float* __restrict__ veh_bih, const float* __restrict__ veh_bhh,
    const float* __restrict__ oWT,
    const float* __restrict__ out_ego_b, const float* __restrict__ out_b,
    const float* __restrict__ mask_input, const float* __restrict__ lane_mask,
    const float* __restrict__ lane_kb, const float* __restrict__ lane_vb,
    float* __restrict__ pred_pos, float* __restrict__ cbuf,
    float* __restrict__ out)
{
    const int b = blockIdx.x;
    const int tid = threadIdx.x;

    __shared__ float  Kbuf[96 * 129];   // K[kvrow][feat], pad 129 (conflict-free b32)
    __shared__ float4 Vt4[128 * 25];    // V^T[feat][kvrow], stride 100 floats
    __shared__ float  tokS[32 * 128];   // tokens -> residual -> x (LN'd)
    __shared__ float  qsS[32 * 128];    // q, then attention output
    __shared__ float  hsS[32 * 128];    // LSTM h, persistent
    __shared__ float4 sc4[32 * 24];     // probs [32][96]; ego-gate / o36 scratch
    __shared__ float  mkS[96];

    float* VtF = (float*)Vt4;
    float* scF = (float*)sc4;

    // split-phase indexing: lane bit 5 = part/k-half
    const int lane = tid & 63, wid = tid >> 6;
    const int fl  = lane & 31, part = lane >> 5;
    const int oct = wid >> 2;                 // 4 octs of 8 agents
    const int fW  = (wid & 3) * 32 + fl;      // feature owned in split phases
    const int nOct = oct * 8;
    const int a0 = part * 4;                  // first owned agent within oct

    // ego gate-parallel indexing
    const int jg = tid >> 1;      // gate 0..511
    const int kh = tid & 1;       // k-half

    // veh bias (gates 0..3 at fW), added by part0 only
    float4 bv4;
    bv4.x = veh_bih[0 * 128 + fW] + veh_bhh[0 * 128 + fW];
    bv4.y = veh_bih[1 * 128 + fW] + veh_bhh[1 * 128 + fW];
    bv4.z = veh_bih[2 * 128 + fW] + veh_bhh[2 * 128 + fW];
    bv4.w = veh_bih[3 * 128 + fW] + veh_bhh[3 * 128 + fW];
    const float bsumE = ego_bih[jg] + ego_bhh[jg];

    // ---- one-time staging: lane K/V (constant), h=0, mask ----
    for (int i = tid; i < 64 * 128; i += 1024) {
        int r = i >> 7, c = i & 127;
        Kbuf[(32 + r) * 129 + c] = lane_kb[((size_t)b * KVN + 32 + r) * F + c];
        VtF[c * 100 + 32 + r]    = lane_vb[((size_t)b * KVN + 32 + r) * F + c];
    }
    for (int i = tid; i < 32 * 128; i += 1024) hsS[i] = 0.f;
    if (tid < 96) mkS[tid] = (tid < 32) ? mask_input[b * 32 + tid] : lane_mask[b * 64 + tid - 32];
    __syncthreads();

#pragma unroll 1
    for (int step = 0; step < HH + LEN; ++step) {
        const int mode = (step >= HH) ? 1 : 0;
        const int t = mode ? 0 : step;

        // ---- P1: build tokens ----
        for (int i = tid; i < 32 * 128; i += 1024) {
            int n = i >> 7, c = i & 127;
            float acc;
            if (mode == 0) {
                acc = conv_b[c];
#pragma unroll
                for (int kt = 0; kt < 3; ++kt) {
                    const float* ip = input + ((size_t)((t + kt) * B + b) * N1 + n) * 2;
                    acc += ip[0] * conv_w[(c * 2 + 0) * 3 + kt] + ip[1] * conv_w[(c * 2 + 1) * 3 + kt];
                }
                const float* hp = hist_pos + ((size_t)(t * B + b) * N1 + n) * 2;
                acc += hp[0] * pos_w[c] + hp[1] * pos_w[128 + c] + pos_b[c];
            } else {
                const float* pp = pred_pos + (size_t)b * 384 + n * 12;
                float mx = 0.f, my = 0.f;
#pragma unroll
                for (int p = 0; p < 6; ++p) { mx += pp[p * 2]; my += pp[p * 2 + 1]; }
                mx *= (1.f / 6.f); my *= (1.f / 6.f);
                acc = hsS[i] + mx * pos_w[c] + my * pos_w[128 + c] + pos_b[c];
            }
            tokS[i] = acc;
        }
        __syncthreads();

        // ---- P2: q/k/v projections; k-half split across lane halves ----
        {
            float aq[8], ak[8], av[8];
#pragma unroll
            for (int a = 0; a < 8; ++a) { aq[a] = 0.f; ak[a] = 0.f; av[a] = 0.f; }
            const int k0 = part * 64;
#pragma unroll 4
            for (int k = 0; k < 64; ++k) {
                float4 w4 = wqkvo[(size_t)(k0 + k) * 128 + fW];
#pragma unroll
                for (int a = 0; a < 8; ++a) {
                    float x = tokS[(nOct + a) * 128 + k0 + k];   // broadcast read
                    aq[a] += x * w4.x; ak[a] += x * w4.y; av[a] += x * w4.z;
                }
            }
#pragma unroll
            for (int a = 0; a < 8; ++a) {
                aq[a] += __shfl_xor(aq[a], 32);
                ak[a] += __shfl_xor(ak[a], 32);
                av[a] += __shfl_xor(av[a], 32);
            }
            // write owned half via register-select (compile-time indices only)
#pragma unroll
            for (int aa = 0; aa < 4; ++aa) {
                float vq, vk, vv;
                switch (aa) {   // aa is a constant after unroll; part-select is v_cndmask
                    case 0: vq = part ? aq[4] : aq[0]; vk = part ? ak[4] : ak[0]; vv = part ? av[4] : av[0]; break;
                    case 1: vq = part ? aq[5] : aq[1]; vk = part ? ak[5] : ak[1]; vv = part ? av[5] : av[1]; break;
                    case 2: vq = part ? aq[6] : aq[2]; vk = part ? ak[6] : ak[2]; vv = part ? av[6] : av[2]; break;
                    default: vq = part ? aq[7] : aq[3]; vk = part ? ak[7] : ak[3]; vv = part ? av[7] : av[3]; break;
                }
                int n = nOct + a0 + aa;
                qsS[n * 128 + fW]  = vq;
                Kbuf[n * 129 + fW] = vk;
                VtF[fW * 100 + n]  = vv;
            }
        }
        __syncthreads();

        // ---- attention, heads sequential ----
#pragma unroll 1
        for (int h = 0; h < NH; ++h) {
            const int hb = h * 16;
            {
                const int rb = (tid >> 6) * 2;
                const bool k2ok = lane < 32;
                float s0[2] = {0, 0}, s1[2] = {0, 0};
                for (int d4 = 0; d4 < 16; d4 += 4) {
                    float4 qv0 = *(const float4*)&qsS[rb * 128 + hb + d4];
                    float4 qv1 = *(const float4*)&qsS[(rb + 1) * 128 + hb + d4];
#pragma unroll
                    for (int kk = 0; kk < 4; ++kk) {
                        float kA = Kbuf[lane * 129 + hb + d4 + kk];
                        float kB = k2ok ? Kbuf[(64 + lane) * 129 + hb + d4 + kk] : 0.f;
                        float q0 = (&qv0.x)[kk], q1 = (&qv1.x)[kk];
                        s0[0] += q0 * kA; s0[1] += q1 * kA;
                        s1[0] += q0 * kB; s1[1] += q1 * kB;
                    }
                }
                float mA = mkS[lane];
                float mB = k2ok ? mkS[64 + lane] : 0.f;
#pragma unroll
                for (int r = 0; r < 2; ++r) {
                    float v0 = (mA > 0.f) ? s0[r] * 0.25f : -1e9f;
                    float v1 = (k2ok && mB > 0.f) ? s1[r] * 0.25f : -1e9f;
                    float mx = fmaxf(v0, v1);
#pragma unroll
                    for (int off = 32; off; off >>= 1) mx = fmaxf(mx, __shfl_xor(mx, off));
                    float e0 = __expf(v0 - mx);
                    float e1 = k2ok ? __expf(v1 - mx) : 0.f;
                    float s = e0 + e1;
#pragma unroll
                    for (int off = 32; off; off >>= 1) s += __shfl_xor(s, off);
                    float inv = 1.f / s;
                    scF[(rb + r) * 96 + lane] = e0 * inv;
                    if (k2ok) scF[(rb + r) * 96 + 64 + lane] = e1 * inv;
                }
            }
            __syncthreads();
            {
                const int pv = tid >> 1, half = tid & 1;
                const int qr = pv >> 4, d = pv & 15;
                const float4* vrow = Vt4 + (hb + d) * 25 + half * 12;
                const float4* srow = sc4 + qr * 24 + half * 12;
                float acc = 0.f;
#pragma unroll
                for (int q4 = 0; q4 < 12; ++q4) {
                    float4 pf = srow[q4], vv = vrow[q4];
                    acc += pf.x * vv.x + pf.y * vv.y + pf.z * vv.z + pf.w * vv.w;
                }
                acc += __shfl_xor(acc, 1);
                if (!half) qsS[qr * 128 + hb + d] = acc;
            }
            __syncthreads();
        }

        // ---- proj + residual; k-half split ----
        {
            float ao[8];
#pragma unroll
            for (int a = 0; a < 8; ++a) ao[a] = 0.f;
            const int k0 = part * 64;
#pragma unroll 4
            for (int k = 0; k < 64; ++k) {
                float w = wo[(size_t)(k0 + k) * 128 + fW];
#pragma unroll
                for (int a = 0; a < 8; ++a)
                    ao[a] += qsS[(nOct + a) * 128 + k0 + k] * w;   // broadcast read
            }
#pragma unroll
            for (int a = 0; a < 8; ++a) ao[a] += __shfl_xor(ao[a], 32);
#pragma unroll
            for (int aa = 0; aa < 4; ++aa) {
                float v;
                switch (aa) {
                    case 0: v = part ? ao[4] : ao[0]; break;
                    case 1: v = part ? ao[5] : ao[1]; break;
                    case 2: v = part ? ao[6] : ao[2]; break;
                    default: v = part ? ao[7] : ao[3]; break;
                }
                tokS[(nOct + a0 + aa) * 128 + fW] += v;
            }
        }
        __syncthreads();

        // ---- LayerNorm in place ----
        {
            const int row = tid >> 5, l = tid & 31;
            float x0 = tokS[row * 128 + l],      x1 = tokS[row * 128 + l + 32];
            float x2 = tokS[row * 128 + l + 64], x3 = tokS[row * 128 + l + 96];
            float s1v = x0 + x1 + x2 + x3;
            float s2v = x0 * x0 + x1 * x1 + x2 * x2 + x3 * x3;
#pragma unroll
            for (int off = 16; off; off >>= 1) {
                s1v += __shfl_xor(s1v, off, 32);
                s2v += __shfl_xor(s2v, off, 32);
            }
            float mean = s1v * (1.f / 128.f);
            float rs = rsqrtf(s2v * (1.f / 128.f) - mean * mean + 1e-5f);
            const float* gg = (row == 0) ? ln_ego_g : ln_g;
            const float* bb = (row == 0) ? ln_ego_b : ln_b;
            tokS[row * 128 + l]      = (x0 - mean) * rs * gg[l]      + bb[l];
            tokS[row * 128 + l + 32] = (x1 - mean) * rs * gg[l + 32] + bb[l + 32];
            tokS[row * 128 + l + 64] = (x2 - mean) * rs * gg[l + 64] + bb[l + 64];
            tokS[row * 128 + l + 96] = (x3 - mean) * rs * gg[l + 96] + bb[l + 96];
        }
        __syncthreads();

        // ---- LSTM cell ----
        {
            // c-state preload for the 4 owned agents
            float coldv[4];
#pragma unroll
            for (int aa = 0; aa < 4; ++aa)
                coldv[aa] = cbuf[((size_t)b * 32 + nOct + a0 + aa) * 128 + fW];

            // ego gates (agent 0), gate-parallel across all 1024 threads
            {
                float accE = kh ? 0.f : bsumE;
                for (int k4 = kh * 16; k4 < kh * 16 + 16; ++k4) {
                    const float4* wp = (const float4*)&egoP2[(size_t)(k4 * 512 + jg) * 8];
                    float4 wi = wp[0], wh = wp[1];
                    float4 xv = *(const float4*)&tokS[k4 * 4];
                    float4 hv = *(const float4*)&hsS[k4 * 4];
                    accE += xv.x * wi.x + xv.y * wi.y + xv.z * wi.z + xv.w * wi.w
                          + hv.x * wh.x + hv.y * wh.y + hv.z * wh.z + hv.w * wh.w;
                }
                accE += __shfl_xor(accE, 1);
                if (!kh) scF[jg] = accE;
            }

            // veh gates: part split (x|h) across lane halves; 8 agents per thread
            const float* srcS = part ? hsS : tokS;
            float4 acc[8];
#pragma unroll
            for (int a = 0; a < 8; ++a) acc[a] = part ? make_float4(0.f, 0.f, 0.f, 0.f) : bv4;
#pragma unroll 4
            for (int k = 0; k < 128; ++k) {
                float4 w4 = *(const float4*)&vehW9[((size_t)(k * 2 + part) * 128 + fW) * 4];
#pragma unroll
                for (int a = 0; a < 8; ++a) {
                    float x = srcS[(nOct + a) * 128 + k];   // broadcast read
                    acc[a].x += x * w4.x; acc[a].y += x * w4.y;
                    acc[a].z += x * w4.z; acc[a].w += x * w4.w;
                }
            }
#pragma unroll
            for (int a = 0; a < 8; ++a) {
                acc[a].x += __shfl_xor(acc[a].x, 32);
                acc[a].y += __shfl_xor(acc[a].y, 32);
                acc[a].z += __shfl_xor(acc[a].z, 32);
                acc[a].w += __shfl_xor(acc[a].w, 32);
            }
            // select owned half into named registers (compile-time indices only)
            float4 g0 = part ? acc[4] : acc[0];
            float4 g1 = part ? acc[5] : acc[1];
            float4 g2 = part ? acc[6] : acc[2];
            float4 g3 = part ? acc[7] : acc[3];
            __syncthreads();   // tok/hs reads + scF(ego) complete before h overwrite
            if (oct == 0 && part == 0) {   // agent 0 -> ego gates (wave-0 lanes 0-31)
                // only the thread owning agent 0 (aa==0) replaces its gates
                g0.x = scF[fW]; g0.y = scF[128 + fW]; g0.z = scF[256 + fW]; g0.w = scF[384 + fW];
            }
#pragma unroll
            for (int aa = 0; aa < 4; ++aa) {
                float4 g4;
                switch (aa) {
                    case 0: g4 = g0; break;
                    case 1: g4 = g1; break;
                    case 2: g4 = g2; break;
                    default: g4 = g3; break;
                }
                const int n = nOct + a0 + aa;
                float c2 = fsigmoid(g4.y) * coldv[aa] + fsigmoid(g4.x) * ftanh(g4.z);
                float h2 = fsigmoid(g4.w) * ftanh(c2);
                cbuf[((size_t)b * 32 + n) * 128 + fW] = c2;
                hsS[n * 128 + fW] = h2;
            }
        }

        // ---- prediction head + pos update + y ----
        if (mode) {
            __syncthreads();   // h2 visible; scF (ego gates) consumed
            if (tid < 288) {
                int jj = tid % 36, g = tid / 36;
                const float* Wv = &oWT[(size_t)(36 + jj) * 128];
                const float* We = &oWT[(size_t)jj * 128];
                float a[4];
                float aE = out_ego_b[jj];
#pragma unroll
                for (int r = 0; r < 4; ++r) a[r] = out_b[jj];
                for (int k2 = 0; k2 < 128; k2 += 4) {
                    float4 wv4 = *(const float4*)&Wv[k2];
#pragma unroll
                    for (int r = 0; r < 4; ++r) {
                        float4 hv = *(const float4*)&hsS[(g * 4 + r) * 128 + k2];
                        a[r] += hv.x * wv4.x + hv.y * wv4.y + hv.z * wv4.z + hv.w * wv4.w;
                    }
                    if (g == 0) {
                        float4 we4 = *(const float4*)&We[k2];
                        float4 hv0 = *(const float4*)&hsS[k2];
                        aE += hv0.x * we4.x + hv0.y * we4.y + hv0.z * we4.z + hv0.w * we4.w;
                    }
                }
                if (g == 0) a[0] = aE;
#pragma unroll
                for (int r = 0; r < 4; ++r) scF[(g * 4 + r) * 36 + jj] = a[r];
            }
            __syncthreads();
            if (tid < 192) {
                int n = tid / 6, p = tid - n * 6;
                float dl = scF[n * 36 + p * 6], yaw = scF[n * 36 + p * 6 + 1];
                float* pp = pred_pos + (size_t)b * 384 + n * 12 + p * 2;
                float px = pp[0] + dl * cosf(yaw);
                float py = pp[1] + dl * sinf(yaw);
                pp[0] = px; pp[1] = py;
                float* y = out + (size_t)(step - HH) * (B * N1 * P6) + ((size_t)b * 32 + n) * 36 + p * 6;
                y[0] = px; y[1] = py;
                y[2] = scF[n * 36 + p * 6 + 2]; y[3] = scF[n * 36 + p * 6 + 3];
                y[4] = scF[n * 36 + p * 6 + 4]; y[5] = scF[n * 36 + p * 6 + 5];
            }
        }
        __syncthreads();   // h, pred_pos ready for next step
    }
}

// ---------------- launcher ----------------
extern "C" void kernel_launch(void* const* d_in, const int* in_sizes, int n_in,
                              void* d_out, int out_size, void* d_ws, size_t ws_size,
                              hipStream_t stream) {
    const float* input      = (const float*)d_in[0];
    const float* init_pos   = (const float*)d_in[1];
    const float* lane_input = (const float*)d_in[2];
    const float* mask_input = (const float*)d_in[3];
    const float* lane_mask  = (const float*)d_in[4];
    const float* conv_w     = (const float*)d_in[5];
    const float* conv_b     = (const float*)d_in[6];
    const float* pos_w      = (const float*)d_in[7];
    const float* pos_b      = (const float*)d_in[8];
    const float* lane_w1    = (const float*)d_in[9];
    const float* lane_b1    = (const float*)d_in[10];
    const float* lane_w2    = (const float*)d_in[11];
    const float* lane_b2    = (const float*)d_in[12];
    const float* lane_to_f  = (const float*)d_in[13];
    const float* wq         = (const float*)d_in[14];
    const float* wk         = (const float*)d_in[15];
    const float* wv         = (const float*)d_in[16];
    const float* wo         = (const float*)d_in[17];
    const float* ln_ego_g   = (const float*)d_in[18];
    const float* ln_ego_b   = (const float*)d_in[19];
    const float* ln_g       = (const float*)d_in[20];
    const float* ln_b       = (const float*)d_in[21];
    const float* ego_wih    = (const float*)d_in[22];
    const float* ego_whh    = (const float*)d_in[23];
    const float* ego_bih    = (const float*)d_in[24];
    const float* ego_bhh    = (const float*)d_in[25];
    const float* veh_wih    = (const float*)d_in[26];
    const float* veh_whh    = (const float*)d_in[27];
    const float* veh_bih    = (const float*)d_in[28];
    const float* veh_bhh    = (const float*)d_in[29];
    const float* out_ego_w  = (const float*)d_in[30];
    const float* out_ego_b  = (const float*)d_in[31];
    const float* out_w      = (const float*)d_in[32];
    const float* out_b      = (const float*)d_in[33];

    float* out = (float*)d_out;
    float* ws = (float*)d_ws;

    // workspace layout (floats)
    float* kv       = ws;                                   // B*KVN*F
    float* kb       = kv + (size_t)B * KVN * F;             // B*KVN*F (lane rows used)
    float* vb       = kb + (size_t)B * KVN * F;             // B*KVN*F
    float* cbuf     = vb + (size_t)B * KVN * F;             // B*N1*F
    float* hist_pos = cbuf + (size_t)B * N1 * F;            // HH*B*N1*2
    float* pred_pos = hist_pos + (size_t)HH * B * N1 * 2;   // B*N1*NP*2
    float* vehW9    = pred_pos + (size_t)B * N1 * NP * 2;   // 128*128*8
    float* egoP2    = vehW9 + (size_t)128 * 128 * 8;        // 32*512*8
    float* wqkvo    = egoP2 + (size_t)32 * 512 * 8;         // 128*128*4
    float* oWT      = wqkvo + (size_t)128 * 128 * 4;        // 2*36*128

    hipMemsetAsync(cbuf, 0, (size_t)B * N1 * F * sizeof(float), stream);
    k_lane_tok<<<B * L, 64, 0, stream>>>(lane_input, lane_w1, lane_b1, lane_w2, lane_b2,
                                         lane_to_f, kv);
    k_hist_pos<<<(B * N1 + 255) / 256, 256, 0, stream>>>(input, init_pos, hist_pos, pred_pos);
    k_build_w9<<<(128 * 128 * 8 + 255) / 256, 256, 0, stream>>>(veh_wih, veh_whh, vehW9);
    k_build_egoP<<<(32 * 512 * 8 + 255) / 256, 256, 0, stream>>>(ego_wih, ego_whh, egoP2);
    k_build_wqkvo<<<(128 * 128 + 255) / 256, 256, 0, stream>>>(wq, wk, wv, wo, (float4*)wqkvo);
    k_build_oWT<<<(2 * 36 * 128 + 255) / 256, 256, 0, stream>>>(out_ego_w, out_w, oWT);
    k_lane_kv<<<B * 8, 256, 0, stream>>>(kv, wk, wv, kb, vb);

    k_mega<<<B, 1024, 0, stream>>>(input, hist_pos, conv_w, conv_b, pos_w, pos_b,
                                   (const float4*)wqkvo, wo,
                                   ln_ego_g, ln_ego_b, ln_g, ln_b,
                                   egoP2, vehW9, ego_bih, ego_bhh, veh_bih, veh_bhh,
                                   oWT, out_ego_b, out_b,
                                   mask_input, lane_mask, kb, vb, pred_pos, cbuf, out);
}

// Round 6
// 8000.677 us; speedup vs baseline: 1.4007x; 1.1172x over previous
//
#include <hip/hip_runtime.h>
#include <hip/hip_bf16.h>
#include <math.h>

// ---------------- constants (fixed by setup_inputs) ----------------
constexpr int B   = 128;   // batch
constexpr int N1  = 32;    // agents (1 ego + 31 veh)
constexpr int HH  = 20;    // history steps (T-2)
constexpr int L   = 64;    // lanes
constexpr int PTS = 10;    // points per lane
constexpr int F   = 128;   // feature size
constexpr int LF  = 64;    // lane feature
constexpr int NH  = 8;     // heads
constexpr int HD  = 16;    // head dim
constexpr int KVN = 96;    // kv tokens = 32 agents + 64 lanes
constexpr int G4  = 512;   // 4*F lstm gates
constexpr int NP  = 6;     // num preds
constexpr int P6  = 36;    // NP*6
constexpr int LEN = 30;    // len_pred

__device__ __forceinline__ float fsigmoid(float x) { return 1.f / (1.f + __expf(-x)); }
__device__ __forceinline__ float ftanh(float x)    { return 1.f - 2.f / (__expf(2.f * x) + 1.f); }

// ---------------- one-time kernels ----------------

__global__ void k_lane_tok(const float* __restrict__ lane_input,
                           const float* __restrict__ w1, const float* __restrict__ b1,
                           const float* __restrict__ w2, const float* __restrict__ b2,
                           const float* __restrict__ to_f,
                           float* __restrict__ kvbuf) {
    int bl = blockIdx.x; int b = bl / L, l = bl % L;
    int tid = threadIdx.x; // 64 threads
    __shared__ float h1[LF][16];
    __shared__ float m[LF];
    const float* xin = lane_input + ((size_t)(b * L + l) * PTS) * 2;
    float w10 = w1[tid], w11 = w1[LF + tid], bb1 = b1[tid];
#pragma unroll
    for (int p = 0; p < PTS; ++p) {
        float v = xin[p * 2] * w10 + xin[p * 2 + 1] * w11 + bb1;
        h1[tid][p] = fmaxf(v, 0.f);
    }
    __syncthreads();
    float ap[PTS];
    float bb2 = b2[tid];
#pragma unroll
    for (int p = 0; p < PTS; ++p) ap[p] = bb2;
    for (int h = 0; h < LF; ++h) {
        float w2v = w2[h * LF + tid];
        float4 x0 = *(const float4*)&h1[h][0];
        float4 x1 = *(const float4*)&h1[h][4];
        float2 x2 = *(const float2*)&h1[h][8];
        ap[0] += x0.x * w2v; ap[1] += x0.y * w2v; ap[2] += x0.z * w2v; ap[3] += x0.w * w2v;
        ap[4] += x1.x * w2v; ap[5] += x1.y * w2v; ap[6] += x1.z * w2v; ap[7] += x1.w * w2v;
        ap[8] += x2.x * w2v; ap[9] += x2.y * w2v;
    }
    float acc = 0.f;
#pragma unroll
    for (int p = 0; p < PTS; ++p) acc += fmaxf(ap[p], 0.f);
    m[tid] = acc * (1.f / PTS);
    __syncthreads();
    float* outp = kvbuf + ((size_t)(b * KVN) + 32 + l) * F;
    for (int f = tid; f < F; f += LF) {
        float s = 0.f;
        for (int j = 0; j < LF; ++j) s += m[j] * to_f[j * F + f];
        outp[f] = s;
    }
}

__global__ void k_lane_kv(const float* __restrict__ kvbuf,
                          const float* __restrict__ wk, const float* __restrict__ wv,
                          float* __restrict__ kb, float* __restrict__ vb) {
    int g = blockIdx.x & 7, b = blockIdx.x >> 3;
    int n0 = 32 + g * 8;
    int tid = threadIdx.x; // 256
    int j = tid & 127, rh = tid >> 7;
    __shared__ float tok[8][F];
    for (int i = tid; i < 8 * F; i += 256) {
        int r = i >> 7, c = i & 127;
        tok[r][c] = kvbuf[((size_t)b * KVN + n0 + r) * F + c];
    }
    __syncthreads();
    float ak[4] = {0, 0, 0, 0}, av[4] = {0, 0, 0, 0};
    int r0 = rh * 4;
    for (int k2 = 0; k2 < F; ++k2) {
        float wkv = wk[k2 * F + j], wvv = wv[k2 * F + j];
#pragma unroll
        for (int r = 0; r < 4; ++r) {
            float x = tok[r0 + r][k2];
            ak[r] += x * wkv; av[r] += x * wvv;
        }
    }
#pragma unroll
    for (int r = 0; r < 4; ++r) {
        int n = n0 + r0 + r;
        kb[((size_t)b * KVN + n) * F + j] = ak[r];
        vb[((size_t)b * KVN + n) * F + j] = av[r];
    }
}

__global__ void k_hist_pos(const float* __restrict__ input,
                           const float* __restrict__ init_pos,
                           float* __restrict__ hist_pos,
                           float* __restrict__ pred_pos) {
    int idx = blockIdx.x * blockDim.x + threadIdx.x;
    if (idx >= B * N1) return;
    float px = init_pos[idx * 2], py = init_pos[idx * 2 + 1];
    int b = idx / N1, n = idx % N1;
    for (int t = 0; t < HH; ++t) {
        const float* ip = input + ((size_t)(t * B + b) * N1 + n) * 2;
        float dl = ip[0], yaw = ip[1];
        px += dl * cosf(yaw);
        py += dl * sinf(yaw);
        float* hp = hist_pos + ((size_t)(t * B + b) * N1 + n) * 2;
        hp[0] = px; hp[1] = py;
    }
#pragma unroll
    for (int p = 0; p < NP; ++p) {
        pred_pos[((size_t)idx * NP + p) * 2 + 0] = px;
        pred_pos[((size_t)idx * NP + p) * 2 + 1] = py;
    }
}

// veh LSTM weights: vehW9[(((k*2 + part)*128 + f)*4 + g)] = (part?whh:wih)[(g*128+f)*128 + k]
__global__ void k_build_w9(const float* __restrict__ wih, const float* __restrict__ whh,
                           float* __restrict__ w9) {
    int i = blockIdx.x * blockDim.x + threadIdx.x;
    if (i >= 128 * 128 * 8) return;
    int g = i & 3, f = (i >> 2) & 127, part = (i >> 9) & 1, k = i >> 10;
    const float* src = part ? whh : wih;
    w9[i] = src[((size_t)(g * 128 + f)) * 128 + k];
}

// ego LSTM weights gate-parallel: egoP[((k4*512 + j)*2 + s)*4 + kk] = W_s[j][k4*4+kk]
__global__ void k_build_egoP(const float* __restrict__ wih, const float* __restrict__ whh,
                             float* __restrict__ egoP) {
    int i = blockIdx.x * blockDim.x + threadIdx.x;
    if (i >= 32 * 512 * 8) return;
    int kk = i & 3, s = (i >> 2) & 1, j = (i >> 3) & 511, k4 = i >> 12;
    int k = k4 * 4 + kk;
    egoP[i] = (s == 0) ? wih[(size_t)j * 128 + k] : whh[(size_t)j * 128 + k];
}

// fuse wq/wk/wv/wo into one float4 per (k,j)
__global__ void k_build_wqkvo(const float* __restrict__ wq, const float* __restrict__ wk,
                              const float* __restrict__ wv, const float* __restrict__ wo,
                              float4* __restrict__ out4) {
    int i = blockIdx.x * blockDim.x + threadIdx.x;
    if (i >= 128 * 128) return;
    out4[i] = make_float4(wq[i], wk[i], wv[i], wo[i]);
}

// transposed output-head weights: oWT[(m*36+jj)*128 + k] = W_m[k*36+jj]
__global__ void k_build_oWT(const float* __restrict__ oe_w, const float* __restrict__ ov_w,
                            float* __restrict__ oWT) {
    int i = blockIdx.x * blockDim.x + threadIdx.x;
    if (i >= 2 * 36 * 128) return;
    int m = i / 4608, r = i % 4608, jj = r >> 7, k = r & 127;
    oWT[i] = (m == 0) ? oe_w[(size_t)k * 36 + jj] : ov_w[(size_t)k * 36 + jj];
}

// ---------------- persistent per-batch mega kernel ----------------
// LDS: Kbuf 49536 + Vt 51200 + tok 16384 + qs 16384 + hs 16384 + sc 12288 + mk 384 = 162560 B
// 159KB LDS => exactly 1 block/CU = 4 waves/EU. amdgpu_waves_per_eu(4,4) raises the
// VGPR budget to the feasible 128 (the default allocator assumed 8 waves/EU -> 64 VGPR
// and spilled the split-phase accumulators to scratch: rounds 3-5's GB-scale WRITE_SIZE).
__global__ __attribute__((amdgpu_flat_work_group_size(1024, 1024), amdgpu_waves_per_eu(4, 4)))
void k_mega(
    const float* __restrict__ input, const float* __restrict__ hist_pos,
    const float* __restrict__ conv_w, const float* __restrict__ conv_b,
    const float* __restrict__ pos_w, const float* __restrict__ pos_b,
    const float4* __restrict__ wqkvo, const float* __restrict__ wo,
    const float* __restrict__ ln_ego_g, const float* __restrict__ ln_ego_b,
    const float* __restrict__ ln_g, const float* __restrict__ ln_b,
    const float* __restrict__ egoP2, const float* __restrict__ vehW9,
    const float* __restrict__ ego_bih, const float* __restrict__ ego_bhh,
    const float* __restrict__ veh_bih, const float* __restrict__ veh_bhh,
    const float* __restrict__ oWT,
    const float* __restrict__ out_ego_b, const float* __restrict__ out_b,
    const float* __restrict__ mask_input, const float* __restrict__ lane_mask,
    const float* __restrict__ lane_kb, const float* __restrict__ lane_vb,
    float* __restrict__ pred_pos, float* __restrict__ cbuf,
    float* __restrict__ out)
{
    const int b = blockIdx.x;
    const int tid = threadIdx.x;

    __shared__ float  Kbuf[96 * 129];   // K[kvrow][feat], pad 129 (conflict-free b32)
    __shared__ float4 Vt4[128 * 25];    // V^T[feat][kvrow], stride 100 floats
    __shared__ float  tokS[32 * 128];   // tokens -> residual -> x (LN'd)
    __shared__ float  qsS[32 * 128];    // q, then attention output
    __shared__ float  hsS[32 * 128];    // LSTM h, persistent
    __shared__ float4 sc4[32 * 24];     // probs [32][96]; ego-gate / o36 scratch
    __shared__ float  mkS[96];

    float* VtF = (float*)Vt4;
    float* scF = (float*)sc4;

    // split-phase indexing: lane bit 5 = part/k-half
    const int lane = tid & 63, wid = tid >> 6;
    const int fl  = lane & 31, part = lane >> 5;
    const int oct = wid >> 2;                 // 4 octs of 8 agents
    const int fW  = (wid & 3) * 32 + fl;      // feature owned in split phases
    const int nOct = oct * 8;
    const int a0 = part * 4;                  // first owned agent within oct

    // ego gate-parallel indexing
    const int jg = tid >> 1;      // gate 0..511
    const int kh = tid & 1;       // k-half

    // veh bias (gates 0..3 at fW), added by part0 only
    float4 bv4;
    bv4.x = veh_bih[0 * 128 + fW] + veh_bhh[0 * 128 + fW];
    bv4.y = veh_bih[1 * 128 + fW] + veh_bhh[1 * 128 + fW];
    bv4.z = veh_bih[2 * 128 + fW] + veh_bhh[2 * 128 + fW];
    bv4.w = veh_bih[3 * 128 + fW] + veh_bhh[3 * 128 + fW];
    const float bsumE = ego_bih[jg] + ego_bhh[jg];

    // ---- one-time staging: lane K/V (constant), h=0, mask ----
    for (int i = tid; i < 64 * 128; i += 1024) {
        int r = i >> 7, c = i & 127;
        Kbuf[(32 + r) * 129 + c] = lane_kb[((size_t)b * KVN + 32 + r) * F + c];
        VtF[c * 100 + 32 + r]    = lane_vb[((size_t)b * KVN + 32 + r) * F + c];
    }
    for (int i = tid; i < 32 * 128; i += 1024) hsS[i] = 0.f;
    if (tid < 96) mkS[tid] = (tid < 32) ? mask_input[b * 32 + tid] : lane_mask[b * 64 + tid - 32];
    __syncthreads();

#pragma unroll 1
    for (int step = 0; step < HH + LEN; ++step) {
        const int mode = (step >= HH) ? 1 : 0;
        const int t = mode ? 0 : step;

        // ---- P1: build tokens ----
        for (int i = tid; i < 32 * 128; i += 1024) {
            int n = i >> 7, c = i & 127;
            float acc;
            if (mode == 0) {
                acc = conv_b[c];
#pragma unroll
                for (int kt = 0; kt < 3; ++kt) {
                    const float* ip = input + ((size_t)((t + kt) * B + b) * N1 + n) * 2;
                    acc += ip[0] * conv_w[(c * 2 + 0) * 3 + kt] + ip[1] * conv_w[(c * 2 + 1) * 3 + kt];
                }
                const float* hp = hist_pos + ((size_t)(t * B + b) * N1 + n) * 2;
                acc += hp[0] * pos_w[c] + hp[1] * pos_w[128 + c] + pos_b[c];
            } else {
                const float* pp = pred_pos + (size_t)b * 384 + n * 12;
                float mx = 0.f, my = 0.f;
#pragma unroll
                for (int p = 0; p < 6; ++p) { mx += pp[p * 2]; my += pp[p * 2 + 1]; }
                mx *= (1.f / 6.f); my *= (1.f / 6.f);
                acc = hsS[i] + mx * pos_w[c] + my * pos_w[128 + c] + pos_b[c];
            }
            tokS[i] = acc;
        }
        __syncthreads();

        // ---- P2: q/k/v projections; k-half split across lane halves ----
        {
            float aq[8], ak[8], av[8];
#pragma unroll
            for (int a = 0; a < 8; ++a) { aq[a] = 0.f; ak[a] = 0.f; av[a] = 0.f; }
            const int k0 = part * 64;
#pragma unroll 2
            for (int k = 0; k < 64; k += 4) {
                float4 w0 = wqkvo[(size_t)(k0 + k + 0) * 128 + fW];
                float4 w1 = wqkvo[(size_t)(k0 + k + 1) * 128 + fW];
                float4 w2 = wqkvo[(size_t)(k0 + k + 2) * 128 + fW];
                float4 w3 = wqkvo[(size_t)(k0 + k + 3) * 128 + fW];
#pragma unroll
                for (int a = 0; a < 8; ++a) {
                    float4 xv = *(const float4*)&tokS[(nOct + a) * 128 + k0 + k];  // broadcast
                    aq[a] += xv.x * w0.x + xv.y * w1.x + xv.z * w2.x + xv.w * w3.x;
                    ak[a] += xv.x * w0.y + xv.y * w1.y + xv.z * w2.y + xv.w * w3.y;
                    av[a] += xv.x * w0.z + xv.y * w1.z + xv.z * w2.z + xv.w * w3.z;
                }
            }
#pragma unroll
            for (int a = 0; a < 8; ++a) {
                aq[a] += __shfl_xor(aq[a], 32);
                ak[a] += __shfl_xor(ak[a], 32);
                av[a] += __shfl_xor(av[a], 32);
            }
            // write owned half via register-select (compile-time indices only)
#pragma unroll
            for (int aa = 0; aa < 4; ++aa) {
                float vq, vk, vv;
                switch (aa) {
                    case 0: vq = part ? aq[4] : aq[0]; vk = part ? ak[4] : ak[0]; vv = part ? av[4] : av[0]; break;
                    case 1: vq = part ? aq[5] : aq[1]; vk = part ? ak[5] : ak[1]; vv = part ? av[5] : av[1]; break;
                    case 2: vq = part ? aq[6] : aq[2]; vk = part ? ak[6] : ak[2]; vv = part ? av[6] : av[2]; break;
                    default: vq = part ? aq[7] : aq[3]; vk = part ? ak[7] : ak[3]; vv = part ? av[7] : av[3]; break;
                }
                int n = nOct + a0 + aa;
                qsS[n * 128 + fW]  = vq;
                Kbuf[n * 129 + fW] = vk;
                VtF[fW * 100 + n]  = vv;
            }
        }
        __syncthreads();

        // ---- attention, heads sequential ----
#pragma unroll 1
        for (int h = 0; h < NH; ++h) {
            const int hb = h * 16;
            {
                const int rb = wid * 2;
                const bool k2ok = lane < 32;
                float s00 = 0.f, s01 = 0.f, s10 = 0.f, s11 = 0.f;
#pragma unroll
                for (int d4 = 0; d4 < 16; d4 += 4) {
                    float4 qv0 = *(const float4*)&qsS[rb * 128 + hb + d4];        // broadcast
                    float4 qv1 = *(const float4*)&qsS[(rb + 1) * 128 + hb + d4];  // broadcast
                    const float* kr0 = &Kbuf[lane * 129 + hb + d4];
                    float kA0 = kr0[0], kA1 = kr0[1], kA2 = kr0[2], kA3 = kr0[3];
                    s00 += qv0.x * kA0 + qv0.y * kA1 + qv0.z * kA2 + qv0.w * kA3;
                    s01 += qv1.x * kA0 + qv1.y * kA1 + qv1.z * kA2 + qv1.w * kA3;
                    if (k2ok) {
                        const float* kr1 = &Kbuf[(64 + lane) * 129 + hb + d4];
                        float kB0 = kr1[0], kB1 = kr1[1], kB2 = kr1[2], kB3 = kr1[3];
                        s10 += qv0.x * kB0 + qv0.y * kB1 + qv0.z * kB2 + qv0.w * kB3;
                        s11 += qv1.x * kB0 + qv1.y * kB1 + qv1.z * kB2 + qv1.w * kB3;
                    }
                }
                float mA = mkS[lane];
                float mB = k2ok ? mkS[64 + lane] : 0.f;
                // row rb
                {
                    float v0 = (mA > 0.f) ? s00 * 0.25f : -1e9f;
                    float v1 = (k2ok && mB > 0.f) ? s10 * 0.25f : -1e9f;
                    float mx = fmaxf(v0, v1);
#pragma unroll
                    for (int off = 32; off; off >>= 1) mx = fmaxf(mx, __shfl_xor(mx, off));
                    float e0 = __expf(v0 - mx);
                    float e1 = k2ok ? __expf(v1 - mx) : 0.f;
                    float s = e0 + e1;
#pragma unroll
                    for (int off = 32; off; off >>= 1) s += __shfl_xor(s, off);
                    float inv = 1.f / s;
                    scF[rb * 96 + lane] = e0 * inv;
                    if (k2ok) scF[rb * 96 + 64 + lane] = e1 * inv;
                }
                // row rb+1
                {
                    float v0 = (mA > 0.f) ? s01 * 0.25f : -1e9f;
                    float v1 = (k2ok && mB > 0.f) ? s11 * 0.25f : -1e9f;
                    float mx = fmaxf(v0, v1);
#pragma unroll
                    for (int off = 32; off; off >>= 1) mx = fmaxf(mx, __shfl_xor(mx, off));
                    float e0 = __expf(v0 - mx);
                    float e1 = k2ok ? __expf(v1 - mx) : 0.f;
                    float s = e0 + e1;
#pragma unroll
                    for (int off = 32; off; off >>= 1) s += __shfl_xor(s, off);
                    float inv = 1.f / s;
                    scF[(rb + 1) * 96 + lane] = e0 * inv;
                    if (k2ok) scF[(rb + 1) * 96 + 64 + lane] = e1 * inv;
                }
            }
            __syncthreads();
            {
                const int pv = tid >> 1, half = tid & 1;
                const int qr = pv >> 4, d = pv & 15;
                const float4* vrow = Vt4 + (hb + d) * 25 + half * 12;
                const float4* srow = sc4 + qr * 24 + half * 12;
                float acc = 0.f;
#pragma unroll
                for (int q4 = 0; q4 < 12; ++q4) {
                    float4 pf = srow[q4], vv = vrow[q4];
                    acc += pf.x * vv.x + pf.y * vv.y + pf.z * vv.z + pf.w * vv.w;
                }
                acc += __shfl_xor(acc, 1);
                if (!half) qsS[qr * 128 + hb + d] = acc;
            }
            __syncthreads();
        }

        // ---- proj + residual; k-half split ----
        {
            float ao[8];
#pragma unroll
            for (int a = 0; a < 8; ++a) ao[a] = 0.f;
            const int k0 = part * 64;
#pragma unroll 2
            for (int k = 0; k < 64; k += 4) {
                float w0 = wo[(size_t)(k0 + k + 0) * 128 + fW];
                float w1 = wo[(size_t)(k0 + k + 1) * 128 + fW];
                float w2 = wo[(size_t)(k0 + k + 2) * 128 + fW];
                float w3 = wo[(size_t)(k0 + k + 3) * 128 + fW];
#pragma unroll
                for (int a = 0; a < 8; ++a) {
                    float4 xv = *(const float4*)&qsS[(nOct + a) * 128 + k0 + k];  // broadcast
                    ao[a] += xv.x * w0 + xv.y * w1 + xv.z * w2 + xv.w * w3;
                }
            }
#pragma unroll
            for (int a = 0; a < 8; ++a) ao[a] += __shfl_xor(ao[a], 32);
#pragma unroll
            for (int aa = 0; aa < 4; ++aa) {
                float v;
                switch (aa) {
                    case 0: v = part ? ao[4] : ao[0]; break;
                    case 1: v = part ? ao[5] : ao[1]; break;
                    case 2: v = part ? ao[6] : ao[2]; break;
                    default: v = part ? ao[7] : ao[3]; break;
                }
                tokS[(nOct + a0 + aa) * 128 + fW] += v;
            }
        }
        __syncthreads();

        // ---- LayerNorm in place ----
        {
            const int row = tid >> 5, l = tid & 31;
            float x0 = tokS[row * 128 + l],      x1 = tokS[row * 128 + l + 32];
            float x2 = tokS[row * 128 + l + 64], x3 = tokS[row * 128 + l + 96];
            float s1v = x0 + x1 + x2 + x3;
            float s2v = x0 * x0 + x1 * x1 + x2 * x2 + x3 * x3;
#pragma unroll
            for (int off = 16; off; off >>= 1) {
                s1v += __shfl_xor(s1v, off, 32);
                s2v += __shfl_xor(s2v, off, 32);
            }
            float mean = s1v * (1.f / 128.f);
            float rs = rsqrtf(s2v * (1.f / 128.f) - mean * mean + 1e-5f);
            const float* gg = (row == 0) ? ln_ego_g : ln_g;
            const float* bb = (row == 0) ? ln_ego_b : ln_b;
            tokS[row * 128 + l]      = (x0 - mean) * rs * gg[l]      + bb[l];
            tokS[row * 128 + l + 32] = (x1 - mean) * rs * gg[l + 32] + bb[l + 32];
            tokS[row * 128 + l + 64] = (x2 - mean) * rs * gg[l + 64] + bb[l + 64];
            tokS[row * 128 + l + 96] = (x3 - mean) * rs * gg[l + 96] + bb[l + 96];
        }
        __syncthreads();

        // ---- LSTM cell ----
        {
            // c-state preload for the 4 owned agents
            float coldv[4];
#pragma unroll
            for (int aa = 0; aa < 4; ++aa)
                coldv[aa] = cbuf[((size_t)b * 32 + nOct + a0 + aa) * 128 + fW];

            // ego gates (agent 0), gate-parallel across all 1024 threads
            {
                float accE = kh ? 0.f : bsumE;
#pragma unroll 4
                for (int k4 = kh * 16; k4 < kh * 16 + 16; ++k4) {
                    const float4* wp = (const float4*)&egoP2[(size_t)(k4 * 512 + jg) * 8];
                    float4 wi = wp[0], wh = wp[1];
                    float4 xv = *(const float4*)&tokS[k4 * 4];
                    float4 hv = *(const float4*)&hsS[k4 * 4];
                    accE += xv.x * wi.x + xv.y * wi.y + xv.z * wi.z + xv.w * wi.w
                          + hv.x * wh.x + hv.y * wh.y + hv.z * wh.z + hv.w * wh.w;
                }
                accE += __shfl_xor(accE, 1);
                if (!kh) scF[jg] = accE;
            }

            // veh gates: part split (x|h) across lane halves; 8 agents per thread
            const float* srcS = part ? hsS : tokS;
            const float4* W9 = (const float4*)vehW9;
            float4 acc[8];
#pragma unroll
            for (int a = 0; a < 8; ++a) acc[a] = part ? make_float4(0.f, 0.f, 0.f, 0.f) : bv4;
#pragma unroll 1
            for (int k = 0; k < 128; k += 4) {
                float4 w0 = W9[(size_t)((k + 0) * 2 + part) * 128 + fW];
                float4 w1 = W9[(size_t)((k + 1) * 2 + part) * 128 + fW];
                float4 w2 = W9[(size_t)((k + 2) * 2 + part) * 128 + fW];
                float4 w3 = W9[(size_t)((k + 3) * 2 + part) * 128 + fW];
#pragma unroll
                for (int a = 0; a < 8; ++a) {
                    float4 xv = *(const float4*)&srcS[(nOct + a) * 128 + k];  // broadcast
                    acc[a].x += xv.x * w0.x + xv.y * w1.x + xv.z * w2.x + xv.w * w3.x;
                    acc[a].y += xv.x * w0.y + xv.y * w1.y + xv.z * w2.y + xv.w * w3.y;
                    acc[a].z += xv.x * w0.z + xv.y * w1.z + xv.z * w2.z + xv.w * w3.z;
                    acc[a].w += xv.x * w0.w + xv.y * w1.w + xv.z * w2.w + xv.w * w3.w;
                }
            }
#pragma unroll
            for (int a = 0; a < 8; ++a) {
                acc[a].x += __shfl_xor(acc[a].x, 32);
                acc[a].y += __shfl_xor(acc[a].y, 32);
                acc[a].z += __shfl_xor(acc[a].z, 32);
                acc[a].w += __shfl_xor(acc[a].w, 32);
            }
            // select owned half into named registers (compile-time indices only)
            float4 g0 = part ? acc[4] : acc[0];
            float4 g1 = part ? acc[5] : acc[1];
            float4 g2 = part ? acc[6] : acc[2];
            float4 g3 = part ? acc[7] : acc[3];
            __syncthreads();   // tok/hs reads + scF(ego) complete before h overwrite
            if (oct == 0 && part == 0) {   // agent 0 -> ego gates
                g0.x = scF[fW]; g0.y = scF[128 + fW]; g0.z = scF[256 + fW]; g0.w = scF[384 + fW];
            }
#pragma unroll
            for (int aa = 0; aa < 4; ++aa) {
                float4 g4;
                switch (aa) {
                    case 0: g4 = g0; break;
                    case 1: g4 = g1; break;
                    case 2: g4 = g2; break;
                    default: g4 = g3; break;
                }
                const int n = nOct + a0 + aa;
                float c2 = fsigmoid(g4.y) * coldv[aa] + fsigmoid(g4.x) * ftanh(g4.z);
                float h2 = fsigmoid(g4.w) * ftanh(c2);
                cbuf[((size_t)b * 32 + n) * 128 + fW] = c2;
                hsS[n * 128 + fW] = h2;
            }
        }

        // ---- prediction head + pos update + y ----
        if (mode) {
            __syncthreads();   // h2 visible; scF (ego gates) consumed
            if (tid < 288) {
                int jj = tid % 36, g = tid / 36;
                const float* Wv = &oWT[(size_t)(36 + jj) * 128];
                const float* We = &oWT[(size_t)jj * 128];
                float a[4];
                float aE = out_ego_b[jj];
#pragma unroll
                for (int r = 0; r < 4; ++r) a[r] = out_b[jj];
                for (int k2 = 0; k2 < 128; k2 += 4) {
                    float4 wv4 = *(const float4*)&Wv[k2];
#pragma unroll
                    for (int r = 0; r < 4; ++r) {
                        float4 hv = *(const float4*)&hsS[(g * 4 + r) * 128 + k2];
                        a[r] += hv.x * wv4.x + hv.y * wv4.y + hv.z * wv4.z + hv.w * wv4.w;
                    }
                    if (g == 0) {
                        float4 we4 = *(const float4*)&We[k2];
                        float4 hv0 = *(const float4*)&hsS[k2];
                        aE += hv0.x * we4.x + hv0.y * we4.y + hv0.z * we4.z + hv0.w * we4.w;
                    }
                }
                if (g == 0) a[0] = aE;
#pragma unroll
                for (int r = 0; r < 4; ++r) scF[(g * 4 + r) * 36 + jj] = a[r];
            }
            __syncthreads();
            if (tid < 192) {
                int n = tid / 6, p = tid - n * 6;
                float dl = scF[n * 36 + p * 6], yaw = scF[n * 36 + p * 6 + 1];
                float* pp = pred_pos + (size_t)b * 384 + n * 12 + p * 2;
                float px = pp[0] + dl * cosf(yaw);
                float py = pp[1] + dl * sinf(yaw);
                pp[0] = px; pp[1] = py;
                float* y = out + (size_t)(step - HH) * (B * N1 * P6) + ((size_t)b * 32 + n) * 36 + p * 6;
                y[0] = px; y[1] = py;
                y[2] = scF[n * 36 + p * 6 + 2]; y[3] = scF[n * 36 + p * 6 + 3];
                y[4] = scF[n * 36 + p * 6 + 4]; y[5] = scF[n * 36 + p * 6 + 5];
            }
        }
        __syncthreads();   // h, pred_pos ready for next step
    }
}

// ---------------- launcher ----------------
extern "C" void kernel_launch(void* const* d_in, const int* in_sizes, int n_in,
                              void* d_out, int out_size, void* d_ws, size_t ws_size,
                              hipStream_t stream) {
    const float* input      = (const float*)d_in[0];
    const float* init_pos   = (const float*)d_in[1];
    const float* lane_input = (const float*)d_in[2];
    const float* mask_input = (const float*)d_in[3];
    const float* lane_mask  = (const float*)d_in[4];
    const float* conv_w     = (const float*)d_in[5];
    const float* conv_b     = (const float*)d_in[6];
    const float* pos_w      = (const float*)d_in[7];
    const float* pos_b      = (const float*)d_in[8];
    const float* lane_w1    = (const float*)d_in[9];
    const float* lane_b1    = (const float*)d_in[10];
    const float* lane_w2    = (const float*)d_in[11];
    const float* lane_b2    = (const float*)d_in[12];
    const float* lane_to_f  = (const float*)d_in[13];
    const float* wq         = (const float*)d_in[14];
    const float* wk         = (const float*)d_in[15];
    const float* wv         = (const float*)d_in[16];
    const float* wo         = (const float*)d_in[17];
    const float* ln_ego_g   = (const float*)d_in[18];
    const float* ln_ego_b   = (const float*)d_in[19];
    const float* ln_g       = (const float*)d_in[20];
    const float* ln_b       = (const float*)d_in[21];
    const float* ego_wih    = (const float*)d_in[22];
    const float* ego_whh    = (const float*)d_in[23];
    const float* ego_bih    = (const float*)d_in[24];
    const float* ego_bhh    = (const float*)d_in[25];
    const float* veh_wih    = (const float*)d_in[26];
    const float* veh_whh    = (const float*)d_in[27];
    const float* veh_bih    = (const float*)d_in[28];
    const float* veh_bhh    = (const float*)d_in[29];
    const float* out_ego_w  = (const float*)d_in[30];
    const float* out_ego_b  = (const float*)d_in[31];
    const float* out_w      = (const float*)d_in[32];
    const float* out_b      = (const float*)d_in[33];

    float* out = (float*)d_out;
    float* ws = (float*)d_ws;

    // workspace layout (floats)
    float* kv       = ws;                                   // B*KVN*F
    float* kb       = kv + (size_t)B * KVN * F;             // B*KVN*F (lane rows used)
    float* vb       = kb + (size_t)B * KVN * F;             // B*KVN*F
    float* cbuf     = vb + (size_t)B * KVN * F;             // B*N1*F
    float* hist_pos = cbuf + (size_t)B * N1 * F;            // HH*B*N1*2
    float* pred_pos = hist_pos + (size_t)HH * B * N1 * 2;   // B*N1*NP*2
    float* vehW9    = pred_pos + (size_t)B * N1 * NP * 2;   // 128*128*8
    float* egoP2    = vehW9 + (size_t)128 * 128 * 8;        // 32*512*8
    float* wqkvo    = egoP2 + (size_t)32 * 512 * 8;         // 128*128*4
    float* oWT      = wqkvo + (size_t)128 * 128 * 4;        // 2*36*128

    hipMemsetAsync(cbuf, 0, (size_t)B * N1 * F * sizeof(float), stream);
    k_lane_tok<<<B * L, 64, 0, stream>>>(lane_input, lane_w1, lane_b1, lane_w2, lane_b2,
                                         lane_to_f, kv);
    k_hist_pos<<<(B * N1 + 255) / 256, 256, 0, stream>>>(input, init_pos, hist_pos, pred_pos);
    k_build_w9<<<(128 * 128 * 8 + 255) / 256, 256, 0, stream>>>(veh_wih, veh_whh, vehW9);
    k_build_egoP<<<(32 * 512 * 8 + 255) / 256, 256, 0, stream>>>(ego_wih, ego_whh, egoP2);
    k_build_wqkvo<<<(128 * 128 + 255) / 256, 256, 0, stream>>>(wq, wk, wv, wo, (float4*)wqkvo);
    k_build_oWT<<<(2 * 36 * 128 + 255) / 256, 256, 0, stream>>>(out_ego_w, out_w, oWT);
    k_lane_kv<<<B * 8, 256, 0, stream>>>(kv, wk, wv, kb, vb);

    k_mega<<<B, 1024, 0, stream>>>(input, hist_pos, conv_w, conv_b, pos_w, pos_b,
                                   (const float4*)wqkvo, wo,
                                   ln_ego_g, ln_ego_b, ln_g, ln_b,
                                   egoP2, vehW9, ego_bih, ego_bhh, veh_bih, veh_bhh,
                                   oWT, out_ego_b, out_b,
                                   mask_input, lane_mask, kb, vb, pred_pos, cbuf, out);
}